// Round 3
// baseline (551.718 us; speedup 1.0000x reference)
//
#include <hip/hip_runtime.h>
#include <hip/hip_bf16.h>

#define CDIM 384
#define NHEADS 12
#define HDIM 32
#define HIDDEN 1536
#define BBATCH 32
#define HH 28
#define WW 28
#define NTOK 784
#define BN (BBATCH * NTOK)   // 25088
#define LN_EPS 1e-5f
#define ATT_SCALE 0.17677669529663687f
#define YTILES 196           // BN / 128
#define PERXCD 25            // ceil(YTILES / 8)

typedef __hip_bfloat16 bf16;
typedef __attribute__((ext_vector_type(8))) short bf16x8;
typedef __attribute__((ext_vector_type(4))) float f32x4;

__device__ __forceinline__ float ldf(const float* p) { return *p; }
__device__ __forceinline__ float ldf(const bf16* p) { return __bfloat162float(*p); }
__device__ __forceinline__ void stf(float* p, float v) { *p = v; }
__device__ __forceinline__ void stf(bf16* p, float v) { *p = __float2bfloat16(v); }

__device__ __forceinline__ short f2bs(float v) {
    bf16 t = __float2bfloat16(v);
    return *reinterpret_cast<short*>(&t);
}

// tanh-form GELU via sigmoid; max |diff| vs exact ~3e-4, well inside tolerance.
__device__ __forceinline__ float gelu_f(float x) {
    float u = x * (0.7978845608f + 0.0356774081f * x * x);
    float e = __expf(-2.f * u);
    return x / (1.f + e);
}

__device__ __forceinline__ void gload16(const void* g, void* l) {
    __builtin_amdgcn_global_load_lds(
        (const __attribute__((address_space(1))) unsigned int*)g,
        (__attribute__((address_space(3))) unsigned int*)l, 16, 0, 0);
}

// ---------------- fp32 -> bf16 weight conversion (all 4 weights, one launch) ------------
__global__ __launch_bounds__(256) void f2b4_k(
    const float* __restrict__ w0, const float* __restrict__ w1,
    const float* __restrict__ w2, const float* __restrict__ w3,
    bf16* __restrict__ dst)
{
    int i = blockIdx.x * 256 + threadIdx.x;   // 0..1769471, dst regions contiguous
    const float* src; int off;
    if (i < 442368)       { src = w0; off = i; }
    else if (i < 589824)  { src = w1; off = i - 442368; }
    else if (i < 1179648) { src = w2; off = i - 589824; }
    else                  { src = w3; off = i - 1179648; }
    dst[i] = __float2bfloat16(src[off]);
}

// ---------------- transpose cpe2 weights (C,9) -> (9,C) ----------------
__global__ __launch_bounds__(256) void wtr_k(const float* __restrict__ w,
                                             float* __restrict__ wt)
{
    int i = blockIdx.x * 256 + threadIdx.x;   // 0..3455
    if (i < 9 * CDIM) {
        int k = i / CDIM, c = i % CDIM;
        wt[i] = w[c * 9 + k];
    }
}

// ---------------- dwconv1 pass A: per-(b,c) plane conv in NCHW, coalesced ----------------
__global__ __launch_bounds__(256) void dwconv_nchw_plane(
    const float* __restrict__ x, const float* __restrict__ w,
    const float* __restrict__ bias, float* __restrict__ y)
{
    __shared__ float sm[NTOK];
    int bc = blockIdx.x;                    // b*CDIM + c
    int c = bc % CDIM;
    const float* xp = x + (size_t)bc * NTOK;
    int tid = threadIdx.x;
#pragma unroll
    for (int i = 0; i < 4; i++) {
        int p = tid + i * 256;
        if (p < NTOK) sm[p] = xp[p];
    }
    __syncthreads();
    const float* wp = w + c * 9;
    float w00 = wp[0], w01 = wp[1], w02 = wp[2];
    float w10 = wp[3], w11 = wp[4], w12 = wp[5];
    float w20 = wp[6], w21 = wp[7], w22 = wp[8];
    float bc_ = bias[c];
    float* yp = y + (size_t)bc * NTOK;
#pragma unroll
    for (int i = 0; i < 4; i++) {
        int p = tid + i * 256;
        if (p >= NTOK) break;
        int h = p / WW, wcol = p % WW;
        bool hm = h > 0, hp = h < HH - 1, wm = wcol > 0, wpv = wcol < WW - 1;
        float s = w11 * sm[p];
        if (hm)        s += w01 * sm[p - WW];
        if (hp)        s += w21 * sm[p + WW];
        if (wm)        s += w10 * sm[p - 1];
        if (wpv)       s += w12 * sm[p + 1];
        if (hm && wm)  s += w00 * sm[p - WW - 1];
        if (hm && wpv) s += w02 * sm[p - WW + 1];
        if (hp && wm)  s += w20 * sm[p + WW - 1];
        if (hp && wpv) s += w22 * sm[p + WW + 1];
        yp[p] = sm[p] + s + bc_;
    }
}

// ---------------- dwconv1 pass B: transpose (B,C,N) -> (B,N,C) ----------------
__global__ __launch_bounds__(256) void transpose_in(
    const float* __restrict__ in, float* __restrict__ out)
{
    __shared__ float t[32][33];
    int b = blockIdx.z;
    int n0 = blockIdx.y * 32;
    int c0 = blockIdx.x * 32;
    int tx = threadIdx.x, ty = threadIdx.y;   // 32 x 8
    for (int i = ty; i < 32; i += 8) {
        int n = n0 + tx;
        if (n < NTOK) t[i][tx] = in[((size_t)b * CDIM + c0 + i) * NTOK + n];
    }
    __syncthreads();
    for (int i = ty; i < 32; i += 8) {
        int n = n0 + i;
        if (n < NTOK) out[((size_t)b * NTOK + n) * CDIM + c0 + tx] = t[tx][i];
    }
}

// ---------------- dwconv2 v2: (B,N,C) layout, float4 channels, XCD-contiguous swizzle ---
__global__ __launch_bounds__(256) void dwconv_bnc_v2(
    const float* __restrict__ xin, const float* __restrict__ wt,
    const float* __restrict__ bias, float* __restrict__ xout)
{
    const int nblk = (BN * 96) / 256;        // 9408
    const int per = nblk >> 3;               // 1176
    int blk = blockIdx.x;
    int blk2 = (blk & 7) * per + (blk >> 3);
    int g4 = blk2 * 256 + threadIdx.x;       // quad index: token*96 + c/4
    int q = g4 % 96;                         // c/4
    int r = g4 / 96;                         // b*NTOK + n
    int c = q * 4;
    int n = r % NTOK, b = r / NTOK;
    int h = n / WW, wcol = n % WW;
    const float4* base = (const float4*)(xin + (size_t)b * NTOK * CDIM);
    bool hm = h > 0, hp = h < HH - 1, wm = wcol > 0, wpv = wcol < WW - 1;

    float4 ctr = base[(size_t)n * 96 + q];
    float4 acc = {0.f, 0.f, 0.f, 0.f};

    const float4* w4 = (const float4*)wt;    // tap k at w4[k*96 + q]
#define TAP(k, cond, dn)                                            \
    if (cond) {                                                     \
        float4 vv = base[(size_t)(n + (dn)) * 96 + q];              \
        float4 ww = w4[(k) * 96 + q];                               \
        acc.x = fmaf(ww.x, vv.x, acc.x);                            \
        acc.y = fmaf(ww.y, vv.y, acc.y);                            \
        acc.z = fmaf(ww.z, vv.z, acc.z);                            \
        acc.w = fmaf(ww.w, vv.w, acc.w);                            \
    }
    TAP(0, hm && wm,   -WW - 1)
    TAP(1, hm,         -WW)
    TAP(2, hm && wpv,  -WW + 1)
    TAP(3, wm,         -1)
    { float4 ww = w4[4 * 96 + q];
      acc.x = fmaf(ww.x, ctr.x, acc.x); acc.y = fmaf(ww.y, ctr.y, acc.y);
      acc.z = fmaf(ww.z, ctr.z, acc.z); acc.w = fmaf(ww.w, ctr.w, acc.w); }
    TAP(5, wpv,        1)
    TAP(6, hp && wm,   WW - 1)
    TAP(7, hp,         WW)
    TAP(8, hp && wpv,  WW + 1)
#undef TAP
    float4 bb = *(const float4*)(bias + c);
    float4 outv;
    outv.x = ctr.x + acc.x + bb.x;
    outv.y = ctr.y + acc.y + bb.y;
    outv.z = ctr.z + acc.z + bb.z;
    outv.w = ctr.w + acc.w + bb.w;
    ((float4*)(xout))[g4] = outv;
}

// ---------------- LayerNorm over C=384, one wave per token; TO = float or bf16 ----------
template <typename TO>
__global__ __launch_bounds__(256) void layernorm_k(
    const float* __restrict__ in, const float* __restrict__ g,
    const float* __restrict__ b, TO* __restrict__ out)
{
    int wid = threadIdx.x >> 6;
    int lane = threadIdx.x & 63;
    size_t r = (size_t)blockIdx.x * 4 + wid;
    const float* row = in + r * CDIM;
    float v[6];
    float s = 0.f;
#pragma unroll
    for (int j = 0; j < 6; j++) { v[j] = row[lane + 64 * j]; s += v[j]; }
#pragma unroll
    for (int off = 32; off >= 1; off >>= 1) s += __shfl_xor(s, off);
    float mu = s * (1.f / CDIM);
    float q = 0.f;
#pragma unroll
    for (int j = 0; j < 6; j++) { float d = v[j] - mu; q += d * d; }
#pragma unroll
    for (int off = 32; off >= 1; off >>= 1) q += __shfl_xor(q, off);
    float rs = rsqrtf(q * (1.f / CDIM) + LN_EPS);
    TO* orow = out + r * CDIM;
#pragma unroll
    for (int j = 0; j < 6; j++) {
        int c = lane + 64 * j;
        stf(&orow[c], (v[j] - mu) * rs * g[c] + b[c]);
    }
}

// ---------------- MFMA GEMM v6: BK=64, A-only LDS, B streamed to registers -------------
// v3/v4/v5 post-mortem: sequential-walls x ~4400cyc wall is invariant across BK /
// buffering / vmcnt discipline (28 walls -> 66-72us). Lever = fewer walls at same
// residency. v6: BK=64 (iters halve: 6 for K=384, 24 for K=1536); LDS holds A only
// (2 x 16KB dbuf, 33KB total with epilogue slab); B-weights are L2-hot (<1.2MB) and
// are loaded straight to registers, prefetched one full iteration ahead (no B DMA,
// no B ds_read, no B barrier dependency). VGPR ~165 -> 3 waves/SIMD (launch_bounds
// (256,3)) -> 3 blocks/CU. A-swizzle for 128B rows: stage colgroup (lane&7)^((lane
// >>3)&7); read group (kh*4+quad)^(lr&7) -> worst 2-way aliasing (free).
template <int ACT, bool RES, typename TO>
__global__ __launch_bounds__(256, 3) void gemm_mfma(
    const short* __restrict__ Abf, const short* __restrict__ Bw,
    const float* __restrict__ bias, const float* __restrict__ res,
    TO* __restrict__ Co, int K, int M, int NX)
{
    int id = blockIdx.x;
    int xcd = id & 7, slot_ = id >> 3;
    int yloc = slot_ / NX, xx = slot_ - yloc * NX;
    int y = xcd * PERXCD + yloc;
    if (y >= YTILES) return;

    __shared__ __align__(16) short lds[16896]; // 33792B: 2 x A-buf 16KB; epilogue slab
    const int tid = threadIdx.x;
    const int wid = tid >> 6, lane = tid & 63;
    const int wrow = wid >> 1, wcol = wid & 1;
    const int quad = lane >> 4, lr = lane & 15;
    const int r0 = y * 128, m0 = xx * 128;

    // A staging: per gload16 instr, 8 rows (lane>>3) x 8 colgroups (lane&7, swizzled)
    const int sg = (lane & 7) ^ ((lane >> 3) & 7);
    const short* gA = Abf + (size_t)(r0 + wid * 32 + (lane >> 3)) * K + sg * 8;

    auto stage = [&](int k0, int p) {
        short* lA = lds + p * 8192 + wid * 2048;
#pragma unroll
        for (int k = 0; k < 4; k++)
            gload16(gA + k0 + (size_t)k * 8 * K, lA + k * 512);
    };

    // B register loads: bv[kh*4+j] = B[m0+wcol*64+j*16+lr][k0+kh*32+quad*8 ..+7]
    const short* gB = Bw + (size_t)(m0 + wcol * 64 + lr) * K + quad * 8;
    bf16x8 b0[8], b1[8];
#define LOADB(bb, k0)                                                        \
    {                                                                        \
        _Pragma("unroll")                                                    \
        for (int kh = 0; kh < 2; kh++)                                       \
            _Pragma("unroll")                                                \
            for (int j = 0; j < 4; j++)                                      \
                bb[kh * 4 + j] = *(const bf16x8*)(gB + (size_t)j * 16 * K +  \
                                                  (k0) + kh * 32);           \
    }

    // A fragment LDS offsets (shorts): row*64 + swizzled group*8
    int rowoff[4];
#pragma unroll
    for (int i = 0; i < 4; i++) rowoff[i] = (wrow * 64 + i * 16 + lr) * 64;
    int slotk[2];
#pragma unroll
    for (int kh = 0; kh < 2; kh++) slotk[kh] = ((kh * 4 + quad) ^ (lr & 7)) * 8;

    f32x4 acc[4][4] = {};

#define COMPUTE(As, bb)                                                      \
    {                                                                        \
        _Pragma("unroll")                                                    \
        for (int kh = 0; kh < 2; kh++) {                                     \
            bf16x8 av[4];                                                    \
            _Pragma("unroll")                                                \
            for (int i = 0; i < 4; i++)                                      \
                av[i] = *(const bf16x8*)((As) + rowoff[i] + slotk[kh]);      \
            _Pragma("unroll")                                                \
            for (int i = 0; i < 4; i++)                                      \
                _Pragma("unroll")                                            \
                for (int j = 0; j < 4; j++)                                  \
                    acc[i][j] = __builtin_amdgcn_mfma_f32_16x16x32_bf16(     \
                        av[i], bb[kh * 4 + j], acc[i][j], 0, 0, 0);          \
        }                                                                    \
    }

    const int nt = K >> 6;                 // 6 or 24 (always even)
    stage(0, 0);
    LOADB(b0, 0);
    __syncthreads();                       // A buf0 + b0 landed (drain)
    for (int t = 0; t < nt; t += 2) {
        if (t + 1 < nt) { stage((t + 1) << 6, 1); LOADB(b1, (t + 1) << 6); }
        COMPUTE(lds, b0);
        __syncthreads();                   // buf1 + b1 ready; buf0 reads done
        if (t + 1 < nt) {
            if (t + 2 < nt) { stage((t + 2) << 6, 0); LOADB(b0, (t + 2) << 6); }
            COMPUTE(lds + 8192, b1);
            __syncthreads();               // buf0 + b0 ready; buf1 reads done
        }
    }
#undef LOADB
#undef COMPUTE

    if constexpr (sizeof(TO) == 4) {
#pragma unroll
        for (int i = 0; i < 4; i++) {
            int gr = r0 + wrow * 64 + i * 16 + quad * 4;
#pragma unroll
            for (int j = 0; j < 4; j++) {
                int gc = m0 + wcol * 64 + j * 16 + lr;
                float bb = bias ? bias[gc] : 0.f;
#pragma unroll
                for (int rr = 0; rr < 4; rr++) {
                    size_t idx = (size_t)(gr + rr) * M + gc;
                    float v = acc[i][j][rr] + bb;
                    if (RES) v += res[idx];
                    if (ACT == 1) v = gelu_f(v);
                    stf((float*)&Co[idx], v);
                }
            }
        }
    } else {
        short* Cs = lds;                   // final __syncthreads already passed
#pragma unroll
        for (int i = 0; i < 4; i++) {
            int lrow = wrow * 64 + i * 16 + quad * 4;
#pragma unroll
            for (int j = 0; j < 4; j++) {
                int lcol = wcol * 64 + j * 16 + lr;
                float bb = bias ? bias[m0 + lcol] : 0.f;
#pragma unroll
                for (int rr = 0; rr < 4; rr++) {
                    float v = acc[i][j][rr] + bb;
                    if (ACT == 1) v = gelu_f(v);
                    Cs[(lrow + rr) * 132 + lcol] = f2bs(v);
                }
            }
        }
        __syncthreads();
        short* co = (short*)Co;
#pragma unroll
        for (int s = 0; s < 16; s++) {
            int row = s * 8 + (tid >> 5);
            int seg = tid & 31;
            uint2 vv = *(const uint2*)(Cs + row * 132 + seg * 4);
            *(uint2*)(co + (size_t)(r0 + row) * M + m0 + seg * 4) = vv;
        }
    }
}

// ---------------- channel attention: attn[b,h,d,e] = softmax_e(SCALE * sum_n k*v) ------
__global__ __launch_bounds__(256) void attn_k(
    const bf16* __restrict__ qkv, float* __restrict__ attn)
{
    int bh = blockIdx.x;
    int b = bh / NHEADS, h = bh % NHEADS;
    __shared__ float ks[64][32];
    __shared__ float vs[64][32];
    __shared__ float sm[32][33];
    int tid = threadIdx.x;
    int d = tid >> 3, e0 = (tid & 7) * 4;
    float acc[4] = {0.f, 0.f, 0.f, 0.f};
    for (int n0 = 0; n0 < NTOK; n0 += 64) {
#pragma unroll
        for (int i = 0; i < 8; i++) {
            int idx = tid + i * 256;
            int nn = idx >> 5, cc = idx & 31;
            int n = n0 + nn;
            float kv = 0.f, vv = 0.f;
            if (n < NTOK) {
                size_t base = ((size_t)b * NTOK + n) * (3 * CDIM);
                kv = ATT_SCALE * __bfloat162float(qkv[base + CDIM + h * HDIM + cc]);
                vv = __bfloat162float(qkv[base + 2 * CDIM + h * HDIM + cc]);
            }
            ks[nn][cc] = kv; vs[nn][cc] = vv;
        }
        __syncthreads();
#pragma unroll 8
        for (int nn = 0; nn < 64; nn++) {
            float kd = ks[nn][d];
#pragma unroll
            for (int j = 0; j < 4; j++) acc[j] += kd * vs[nn][e0 + j];
        }
        __syncthreads();
    }
#pragma unroll
    for (int j = 0; j < 4; j++) sm[d][e0 + j] = acc[j];
    __syncthreads();
    if (tid < 32) {
        float mx = -1e30f;
#pragma unroll
        for (int e = 0; e < 32; e++) mx = fmaxf(mx, sm[tid][e]);
        float ssum = 0.f;
        float ex[32];
#pragma unroll
        for (int e = 0; e < 32; e++) { ex[e] = expf(sm[tid][e] - mx); ssum += ex[e]; }
        float inv = 1.f / ssum;
        float* arow = attn + ((size_t)bh * 32 + tid) * 32;
#pragma unroll
        for (int e = 0; e < 32; e++) arow[e] = ex[e] * inv;
    }
}

// ---------------- apply attention v2: attn row in registers, 8-token staged chunks -----
__global__ __launch_bounds__(384) void apply_attn_k(
    const bf16* __restrict__ qkv, const float* __restrict__ attn,
    bf16* __restrict__ out)
{
    int b = blockIdx.x;
    int chunk = blockIdx.y;            // 14 chunks of 56 tokens
    int tid = threadIdx.x;             // 0..383
    int h = tid >> 5;
    __shared__ float qs[8][CDIM];
    float at[32];
    const float4* ap = (const float4*)(attn + ((size_t)(b * NHEADS) * 32 + tid) * 32);
#pragma unroll
    for (int e4 = 0; e4 < 8; e4++) {
        float4 v = ap[e4];
        at[e4 * 4 + 0] = v.x; at[e4 * 4 + 1] = v.y;
        at[e4 * 4 + 2] = v.z; at[e4 * 4 + 3] = v.w;
    }
    int nbase = chunk * 56;
    for (int t0 = 0; t0 < 56; t0 += 8) {
        __syncthreads();
#pragma unroll
        for (int i = 0; i < 8; i++) {
            int n = nbase + t0 + i;
            qs[i][tid] = __bfloat162float(qkv[((size_t)b * NTOK + n) * (3 * CDIM) + tid]);
        }
        __syncthreads();
#pragma unroll
        for (int i = 0; i < 8; i++) {
            const float* qrow = &qs[i][h * 32];
            float s = 0.f;
#pragma unroll
            for (int e = 0; e < 32; e++) s += at[e] * qrow[e];
            int n = nbase + t0 + i;
            out[((size_t)b * NTOK + n) * CDIM + tid] = __float2bfloat16(s);
        }
    }
}

// ---------------- final transpose: (B,N,C) -> (B,C,H,W) ----------------
__global__ __launch_bounds__(256) void transpose_out(
    const float* __restrict__ in, float* __restrict__ out)
{
    __shared__ float t[32][33];
    int b = blockIdx.z;
    int n0 = blockIdx.y * 32;
    int c0 = blockIdx.x * 32;
    int tx = threadIdx.x, ty = threadIdx.y;   // 32 x 8
    for (int i = ty; i < 32; i += 8) {
        int n = n0 + i;
        if (n < NTOK) t[i][tx] = in[((size_t)b * NTOK + n) * CDIM + c0 + tx];
    }
    __syncthreads();
    for (int i = ty; i < 32; i += 8) {
        int c = c0 + i;
        int n = n0 + tx;
        if (n < NTOK) out[((size_t)b * CDIM + c) * NTOK + n] = t[tx][i];
    }
}

extern "C" void kernel_launch(void* const* d_in, const int* in_sizes, int n_in,
                              void* d_out, int out_size, void* d_ws, size_t ws_size,
                              hipStream_t stream) {
    const float* x      = (const float*)d_in[0];
    const float* cpe1_w = (const float*)d_in[1];
    const float* cpe1_b = (const float*)d_in[2];
    const float* n1g    = (const float*)d_in[3];
    const float* n1b    = (const float*)d_in[4];
    const float* qkv_w  = (const float*)d_in[5];
    const float* proj_w = (const float*)d_in[6];
    const float* proj_b = (const float*)d_in[7];
    const float* cpe2_w = (const float*)d_in[8];
    const float* cpe2_b = (const float*)d_in[9];
    const float* n2g    = (const float*)d_in[10];
    const float* n2b    = (const float*)d_in[11];
    const float* fc1_w  = (const float*)d_in[12];
    const float* fc1_b  = (const float*)d_in[13];
    const float* fc2_w  = (const float*)d_in[14];
    const float* fc2_b  = (const float*)d_in[15];

    const size_t A = (size_t)BN * CDIM;        // 9,633,792
    const size_t HA = A / 2;

    // bf16 weights contiguous at front of ws
    bf16* wqkv  = (bf16*)d_ws;                 // 442368
    bf16* wproj = wqkv + 442368;               // 147456
    bf16* wfc1  = wproj + 147456;              // 589824
    bf16* wfc2  = wfc1 + 589824;               // 589824
    float* base = (float*)d_ws + 884736;

    float* xt        = base;                   // [0, A)        residual stream
    bf16*  curb      = (bf16*)(base + A);      // [A, 1.5A)     LN1 out (bf16)
    bf16*  ylnb      = (bf16*)(base + A);      // phase-2 reuse LN2 out (bf16)
    bf16*  qkvb      = (bf16*)(base + A + HA); // [1.5A, 3A)    qkv (bf16, 3A elems)
    float* x3        = base + A + HA;          // phase-2 reuse [1.5A, 2.5A)
    bf16*  h1        = (bf16*)(base + A + HA + A); // [2.5A, 4.5A) fc1 out (bf16)
    float* attnm     = base + 3 * A;           // [3A, +393216)
    bf16*  attn_outb = (bf16*)(base + 3 * A + 393216);
    float* finalb    = base;                   // xt region reuse
    float* xconv     = base + (A * 7) / 2;     // [3.5A, 4.5A)  dwconv1 NCHW temp
    float* cpe2_wt   = base + (A * 9) / 2;     // [4.5A, +3456) transposed taps

    const int GEMM_GRID3  = 8 * PERXCD * 3;    // 600
    const int GEMM_GRID9  = 8 * PERXCD * 9;    // 1800
    const int GEMM_GRID12 = 8 * PERXCD * 12;   // 2400

    // 0. weight conversion fp32 -> bf16 (single launch) + cpe2 tap transpose
    f2b4_k<<<1769472 / 256, 256, 0, stream>>>(qkv_w, proj_w, fc1_w, fc2_w, wqkv);
    wtr_k<<<14, 256, 0, stream>>>(cpe2_w, cpe2_wt);

    // 1a. cpe1 + residual in NCHW (coalesced, LDS-planed)
    dwconv_nchw_plane<<<BBATCH * CDIM, 256, 0, stream>>>(x, cpe1_w, cpe1_b, xconv);
    // 1b. transpose (B,C,N) -> (B,N,C)
    transpose_in<<<dim3(CDIM / 32, (NTOK + 31) / 32, BBATCH), dim3(32, 8), 0, stream>>>(
        xconv, xt);
    // 2. LN1 -> bf16
    layernorm_k<bf16><<<BN / 4, 256, 0, stream>>>(xt, n1g, n1b, curb);
    // 3. qkv GEMM (bf16 MFMA, out bf16)
    gemm_mfma<0, false, bf16><<<GEMM_GRID9, 256, 0, stream>>>(
        (const short*)curb, (const short*)wqkv, nullptr, nullptr, qkvb, 384, 1152, 9);
    // 4. channel attention matrices + softmax
    attn_k<<<BBATCH * NHEADS, 256, 0, stream>>>(qkvb, attnm);
    // 5. apply attention to q (out bf16)
    apply_attn_k<<<dim3(BBATCH, 14), 384, 0, stream>>>(qkvb, attnm, attn_outb);
    // 6. proj GEMM + bias + residual (in-place into xt)
    gemm_mfma<0, true, float><<<GEMM_GRID3, 256, 0, stream>>>(
        (const short*)attn_outb, (const short*)wproj, proj_b, xt, xt, 384, 384, 3);
    // 7. cpe2 + residual in (B,N,C)  — XCD-swizzled, float4
    dwconv_bnc_v2<<<(BN * 96) / 256, 256, 0, stream>>>(xt, cpe2_wt, cpe2_b, x3);
    // 8. LN2 -> bf16
    layernorm_k<bf16><<<BN / 4, 256, 0, stream>>>(x3, n2g, n2b, ylnb);
    // 9. fc1 + bias + GELU (out bf16)
    gemm_mfma<1, false, bf16><<<GEMM_GRID12, 256, 0, stream>>>(
        (const short*)ylnb, (const short*)wfc1, fc1_b, nullptr, h1, 384, 1536, 12);
    // 10. fc2 + bias + residual(x3)
    gemm_mfma<0, true, float><<<GEMM_GRID3, 256, 0, stream>>>(
        (const short*)h1, (const short*)wfc2, fc2_b, x3, finalb, 1536, 384, 3);
    // 11. (B,N,C) -> (B,C,H,W)
    transpose_out<<<dim3(CDIM / 32, (NTOK + 31) / 32, BBATCH), dim3(32, 8), 0, stream>>>(
        finalb, (float*)d_out);
}

// Round 4
// 486.365 us; speedup vs baseline: 1.1344x; 1.1344x over previous
//
#include <hip/hip_runtime.h>
#include <hip/hip_bf16.h>

#define CDIM 384
#define NHEADS 12
#define HDIM 32
#define HIDDEN 1536
#define BBATCH 32
#define HH 28
#define WW 28
#define NTOK 784
#define BN (BBATCH * NTOK)   // 25088
#define LN_EPS 1e-5f
#define ATT_SCALE 0.17677669529663687f
#define YT2 98               // BN / 256 row-tiles
#define PERXCD2 13           // ceil(98 / 8)

typedef __hip_bfloat16 bf16;
typedef __attribute__((ext_vector_type(8))) short bf16x8;
typedef __attribute__((ext_vector_type(4))) float f32x4;

__device__ __forceinline__ float ldf(const float* p) { return *p; }
__device__ __forceinline__ float ldf(const bf16* p) { return __bfloat162float(*p); }
__device__ __forceinline__ void stf(float* p, float v) { *p = v; }
__device__ __forceinline__ void stf(bf16* p, float v) { *p = __float2bfloat16(v); }

__device__ __forceinline__ short f2bs(float v) {
    bf16 t = __float2bfloat16(v);
    return *reinterpret_cast<short*>(&t);
}

// tanh-form GELU via sigmoid; max |diff| vs exact ~3e-4, well inside tolerance.
__device__ __forceinline__ float gelu_f(float x) {
    float u = x * (0.7978845608f + 0.0356774081f * x * x);
    float e = __expf(-2.f * u);
    return x / (1.f + e);
}

__device__ __forceinline__ void gload16(const void* g, void* l) {
    __builtin_amdgcn_global_load_lds(
        (const __attribute__((address_space(1))) unsigned int*)g,
        (__attribute__((address_space(3))) unsigned int*)l, 16, 0, 0);
}

// ---------------- fp32 -> bf16 weight conversion (all 4 weights, one launch) ------------
__global__ __launch_bounds__(256) void f2b4_k(
    const float* __restrict__ w0, const float* __restrict__ w1,
    const float* __restrict__ w2, const float* __restrict__ w3,
    bf16* __restrict__ dst)
{
    int i = blockIdx.x * 256 + threadIdx.x;   // 0..1769471, dst regions contiguous
    const float* src; int off;
    if (i < 442368)       { src = w0; off = i; }
    else if (i < 589824)  { src = w1; off = i - 442368; }
    else if (i < 1179648) { src = w2; off = i - 589824; }
    else                  { src = w3; off = i - 1179648; }
    dst[i] = __float2bfloat16(src[off]);
}

// ---------------- transpose cpe2 weights (C,9) -> (9,C) ----------------
__global__ __launch_bounds__(256) void wtr_k(const float* __restrict__ w,
                                             float* __restrict__ wt)
{
    int i = blockIdx.x * 256 + threadIdx.x;   // 0..3455
    if (i < 9 * CDIM) {
        int k = i / CDIM, c = i % CDIM;
        wt[i] = w[c * 9 + k];
    }
}

// ---------------- dwconv1 pass A: per-(b,c) plane conv in NCHW, coalesced ----------------
__global__ __launch_bounds__(256) void dwconv_nchw_plane(
    const float* __restrict__ x, const float* __restrict__ w,
    const float* __restrict__ bias, float* __restrict__ y)
{
    __shared__ float sm[NTOK];
    int bc = blockIdx.x;                    // b*CDIM + c
    int c = bc % CDIM;
    const float* xp = x + (size_t)bc * NTOK;
    int tid = threadIdx.x;
#pragma unroll
    for (int i = 0; i < 4; i++) {
        int p = tid + i * 256;
        if (p < NTOK) sm[p] = xp[p];
    }
    __syncthreads();
    const float* wp = w + c * 9;
    float w00 = wp[0], w01 = wp[1], w02 = wp[2];
    float w10 = wp[3], w11 = wp[4], w12 = wp[5];
    float w20 = wp[6], w21 = wp[7], w22 = wp[8];
    float bc_ = bias[c];
    float* yp = y + (size_t)bc * NTOK;
#pragma unroll
    for (int i = 0; i < 4; i++) {
        int p = tid + i * 256;
        if (p >= NTOK) break;
        int h = p / WW, wcol = p % WW;
        bool hm = h > 0, hp = h < HH - 1, wm = wcol > 0, wpv = wcol < WW - 1;
        float s = w11 * sm[p];
        if (hm)        s += w01 * sm[p - WW];
        if (hp)        s += w21 * sm[p + WW];
        if (wm)        s += w10 * sm[p - 1];
        if (wpv)       s += w12 * sm[p + 1];
        if (hm && wm)  s += w00 * sm[p - WW - 1];
        if (hm && wpv) s += w02 * sm[p - WW + 1];
        if (hp && wm)  s += w20 * sm[p + WW - 1];
        if (hp && wpv) s += w22 * sm[p + WW + 1];
        yp[p] = sm[p] + s + bc_;
    }
}

// ---------------- dwconv1 pass B: transpose (B,C,N) -> (B,N,C) ----------------
__global__ __launch_bounds__(256) void transpose_in(
    const float* __restrict__ in, float* __restrict__ out)
{
    __shared__ float t[32][33];
    int b = blockIdx.z;
    int n0 = blockIdx.y * 32;
    int c0 = blockIdx.x * 32;
    int tx = threadIdx.x, ty = threadIdx.y;   // 32 x 8
    for (int i = ty; i < 32; i += 8) {
        int n = n0 + tx;
        if (n < NTOK) t[i][tx] = in[((size_t)b * CDIM + c0 + i) * NTOK + n];
    }
    __syncthreads();
    for (int i = ty; i < 32; i += 8) {
        int n = n0 + i;
        if (n < NTOK) out[((size_t)b * NTOK + n) * CDIM + c0 + tx] = t[tx][i];
    }
}

// ---------------- dwconv2 v2: (B,N,C) layout, float4 channels, XCD-contiguous swizzle ---
__global__ __launch_bounds__(256) void dwconv_bnc_v2(
    const float* __restrict__ xin, const float* __restrict__ wt,
    const float* __restrict__ bias, float* __restrict__ xout)
{
    const int nblk = (BN * 96) / 256;        // 9408
    const int per = nblk >> 3;               // 1176
    int blk = blockIdx.x;
    int blk2 = (blk & 7) * per + (blk >> 3);
    int g4 = blk2 * 256 + threadIdx.x;       // quad index: token*96 + c/4
    int q = g4 % 96;                         // c/4
    int r = g4 / 96;                         // b*NTOK + n
    int c = q * 4;
    int n = r % NTOK, b = r / NTOK;
    int h = n / WW, wcol = n % WW;
    const float4* base = (const float4*)(xin + (size_t)b * NTOK * CDIM);
    bool hm = h > 0, hp = h < HH - 1, wm = wcol > 0, wpv = wcol < WW - 1;

    float4 ctr = base[(size_t)n * 96 + q];
    float4 acc = {0.f, 0.f, 0.f, 0.f};

    const float4* w4 = (const float4*)wt;    // tap k at w4[k*96 + q]
#define TAP(k, cond, dn)                                            \
    if (cond) {                                                     \
        float4 vv = base[(size_t)(n + (dn)) * 96 + q];              \
        float4 ww = w4[(k) * 96 + q];                               \
        acc.x = fmaf(ww.x, vv.x, acc.x);                            \
        acc.y = fmaf(ww.y, vv.y, acc.y);                            \
        acc.z = fmaf(ww.z, vv.z, acc.z);                            \
        acc.w = fmaf(ww.w, vv.w, acc.w);                            \
    }
    TAP(0, hm && wm,   -WW - 1)
    TAP(1, hm,         -WW)
    TAP(2, hm && wpv,  -WW + 1)
    TAP(3, wm,         -1)
    { float4 ww = w4[4 * 96 + q];
      acc.x = fmaf(ww.x, ctr.x, acc.x); acc.y = fmaf(ww.y, ctr.y, acc.y);
      acc.z = fmaf(ww.z, ctr.z, acc.z); acc.w = fmaf(ww.w, ctr.w, acc.w); }
    TAP(5, wpv,        1)
    TAP(6, hp && wm,   WW - 1)
    TAP(7, hp,         WW)
    TAP(8, hp && wpv,  WW + 1)
#undef TAP
    float4 bb = *(const float4*)(bias + c);
    float4 outv;
    outv.x = ctr.x + acc.x + bb.x;
    outv.y = ctr.y + acc.y + bb.y;
    outv.z = ctr.z + acc.z + bb.z;
    outv.w = ctr.w + acc.w + bb.w;
    ((float4*)(xout))[g4] = outv;
}

// ---------------- LayerNorm over C=384, one wave per token; TO = float or bf16 ----------
template <typename TO>
__global__ __launch_bounds__(256) void layernorm_k(
    const float* __restrict__ in, const float* __restrict__ g,
    const float* __restrict__ b, TO* __restrict__ out)
{
    int wid = threadIdx.x >> 6;
    int lane = threadIdx.x & 63;
    size_t r = (size_t)blockIdx.x * 4 + wid;
    const float* row = in + r * CDIM;
    float v[6];
    float s = 0.f;
#pragma unroll
    for (int j = 0; j < 6; j++) { v[j] = row[lane + 64 * j]; s += v[j]; }
#pragma unroll
    for (int off = 32; off >= 1; off >>= 1) s += __shfl_xor(s, off);
    float mu = s * (1.f / CDIM);
    float q = 0.f;
#pragma unroll
    for (int j = 0; j < 6; j++) { float d = v[j] - mu; q += d * d; }
#pragma unroll
    for (int off = 32; off >= 1; off >>= 1) q += __shfl_xor(q, off);
    float rs = rsqrtf(q * (1.f / CDIM) + LN_EPS);
    TO* orow = out + r * CDIM;
#pragma unroll
    for (int j = 0; j < 6; j++) {
        int c = lane + 64 * j;
        stf(&orow[c], (v[j] - mu) * rs * g[c] + b[c]);
    }
}

// ---------------- MFMA GEMM v7: phase-split counted-vmcnt schedule (T3+T4+T5) ----------
// BM=256 x BN=128 tile, 512 thr / 8 waves (4 row x 2 col), per-wave 64x64 (4x4 frags).
// Stage granularity = half-K-tile (32): A 256x32 (16KB) + B 128x32 (8KB) = 24KB/slot,
// 4 slots = 96KB LDS, 3 halves always in flight. Per phase: 8 ds_read_b128 + 3
// global_load_lds + s_waitcnt vmcnt(6) (never 0 until tail) + 2 s_barrier + setprio(1)
// around a 16-MFMA cluster. v1-v6 post-mortem: the 2-phase {stage, drain-barrier,
// read, mfma} wall is ~4.4-5.6K cyc/iter regardless of BK/buffers/occupancy; the
// phase-split + counted-vmcnt is the proven lever (+28-73%, learn_hip m196/m218).
// Swizzle = v5's measured-conflict-free map: colgroup g of row r at slot g^((r>>1)&3),
// staged via pre-swizzled global source + linear LDS dest.
template <int ACT, bool RES, typename TO, int K>
__global__ __launch_bounds__(512, 2) void gemm_mfma8(
    const short* __restrict__ Abf, const short* __restrict__ Bw,
    const float* __restrict__ bias, const float* __restrict__ res,
    TO* __restrict__ Co, int M, int NX)
{
    int id = blockIdx.x;
    int xcd = id & 7, slot_ = id >> 3;
    int yloc = slot_ / NX, xx = slot_ - yloc * NX;
    int y = xcd * PERXCD2 + yloc;
    if (y >= YT2) return;

    __shared__ __align__(16) short lds[49152];   // 96KB: 4 slots x (A 8192 | B 4096) sh
    const int tid = threadIdx.x;
    const int wid = tid >> 6, lane = tid & 63;
    const int wr = wid >> 1, wc = wid & 1;
    const int quad = lane >> 4, lr = lane & 15;
    const int r0 = y * 256, m0 = xx * 128;

    // staging: per thread 2 A-loads + 1 B-load per half; dest linear, source swizzled
    const int sg = (lane & 3) ^ ((lane >> 3) & 3);   // source colgroup
    const short* gA = Abf + (size_t)(r0 + wid * 16 + (lane >> 2)) * K + sg * 8;
    const short* gB = Bw  + (size_t)(m0 + wid * 16 + (lane >> 2)) * K + sg * 8;

    auto stage = [&](int h) {
        const int sl = h & 3;
        short* lA = lds + sl * 12288 + wid * 512;
        short* lB = lds + sl * 12288 + 8192 + wid * 512;
        const size_t kof = (size_t)h * 32;
        gload16(gA + kof, lA);                          // A rows 0..127
        gload16(gA + kof + (size_t)128 * K, lA + 4096); // A rows 128..255
        gload16(gB + kof, lB);                          // B rows 0..127
    };

    // fragment read offsets (shorts, within slot); slot = quad ^ ((lr>>1)&3)
    const int ksl = (quad ^ ((lr >> 1) & 3)) * 8;
    int fA[4], fB[4];
#pragma unroll
    for (int i = 0; i < 4; i++) {
        fA[i] = (wr * 64 + i * 16 + lr) * 32 + ksl;
        fB[i] = 8192 + (wc * 64 + i * 16 + lr) * 32 + ksl;
    }

    f32x4 acc[4][4] = {};

    constexpr int NH = K / 32;          // 12 or 48
    stage(0); stage(1); stage(2);       // 9 loads in flight
    asm volatile("s_waitcnt vmcnt(6)" ::: "memory");   // half 0 landed
    __builtin_amdgcn_s_barrier();
    __builtin_amdgcn_sched_barrier(0);

    for (int h = 0; h < NH; ++h) {
        const short* S = lds + (h & 3) * 12288;
        bf16x8 av[4], bv[4];
#pragma unroll
        for (int i = 0; i < 4; i++) {
            av[i] = *(const bf16x8*)(S + fA[i]);
            bv[i] = *(const bf16x8*)(S + fB[i]);
        }
        __builtin_amdgcn_sched_barrier(0);
        if (h + 3 < NH) stage(h + 3);
        __builtin_amdgcn_sched_barrier(0);
        if (h < NH - 3)       { asm volatile("s_waitcnt vmcnt(6)" ::: "memory"); }
        else if (h == NH - 3) { asm volatile("s_waitcnt vmcnt(3)" ::: "memory"); }
        else if (h == NH - 2) { asm volatile("s_waitcnt vmcnt(0)" ::: "memory"); }
        __builtin_amdgcn_s_barrier();     // next half validated for all waves
        __builtin_amdgcn_sched_barrier(0);
        __builtin_amdgcn_s_setprio(1);
#pragma unroll
        for (int i = 0; i < 4; i++)
#pragma unroll
            for (int j = 0; j < 4; j++)
                acc[i][j] = __builtin_amdgcn_mfma_f32_16x16x32_bf16(
                    av[i], bv[j], acc[i][j], 0, 0, 0);
        __builtin_amdgcn_s_setprio(0);
        __builtin_amdgcn_sched_barrier(0);
        __builtin_amdgcn_s_barrier();     // all waves' reads of this slot done
    }

    if constexpr (sizeof(TO) == 4) {
#pragma unroll
        for (int i = 0; i < 4; i++) {
            int gr = r0 + wr * 64 + i * 16 + quad * 4;
#pragma unroll
            for (int j = 0; j < 4; j++) {
                int gc = m0 + wc * 64 + j * 16 + lr;
                float bb = bias ? bias[gc] : 0.f;
#pragma unroll
                for (int rr = 0; rr < 4; rr++) {
                    size_t idx = (size_t)(gr + rr) * M + gc;
                    float v = acc[i][j][rr] + bb;
                    if (RES) v += res[idx];
                    if (ACT == 1) v = gelu_f(v);
                    stf((float*)&Co[idx], v);
                }
            }
        }
    } else {
        short* Cs = lds;                  // 256 x 132 shorts = 67.5KB, fits
#pragma unroll
        for (int i = 0; i < 4; i++) {
            int lrow = wr * 64 + i * 16 + quad * 4;
#pragma unroll
            for (int j = 0; j < 4; j++) {
                int lcol = wc * 64 + j * 16 + lr;
                float bb = bias ? bias[m0 + lcol] : 0.f;
#pragma unroll
                for (int rr = 0; rr < 4; rr++) {
                    float v = acc[i][j][rr] + bb;
                    if (ACT == 1) v = gelu_f(v);
                    Cs[(lrow + rr) * 132 + lcol] = f2bs(v);
                }
            }
        }
        __syncthreads();
        short* co = (short*)Co;
#pragma unroll
        for (int s = 0; s < 16; s++) {
            int row = s * 16 + (tid >> 5);       // 256 rows
            int seg = tid & 31;                  // 32 x 4-short segments = 128 cols
            uint2 vv = *(const uint2*)(Cs + row * 132 + seg * 4);
            *(uint2*)(co + (size_t)(r0 + row) * M + m0 + seg * 4) = vv;
        }
    }
}

// ---------------- channel attention: attn[b,h,d,e] = softmax_e(SCALE * sum_n k*v) ------
__global__ __launch_bounds__(256) void attn_k(
    const bf16* __restrict__ qkv, float* __restrict__ attn)
{
    int bh = blockIdx.x;
    int b = bh / NHEADS, h = bh % NHEADS;
    __shared__ float ks[64][32];
    __shared__ float vs[64][32];
    __shared__ float sm[32][33];
    int tid = threadIdx.x;
    int d = tid >> 3, e0 = (tid & 7) * 4;
    float acc[4] = {0.f, 0.f, 0.f, 0.f};
    for (int n0 = 0; n0 < NTOK; n0 += 64) {
#pragma unroll
        for (int i = 0; i < 8; i++) {
            int idx = tid + i * 256;
            int nn = idx >> 5, cc = idx & 31;
            int n = n0 + nn;
            float kv = 0.f, vv = 0.f;
            if (n < NTOK) {
                size_t base = ((size_t)b * NTOK + n) * (3 * CDIM);
                kv = ATT_SCALE * __bfloat162float(qkv[base + CDIM + h * HDIM + cc]);
                vv = __bfloat162float(qkv[base + 2 * CDIM + h * HDIM + cc]);
            }
            ks[nn][cc] = kv; vs[nn][cc] = vv;
        }
        __syncthreads();
#pragma unroll 8
        for (int nn = 0; nn < 64; nn++) {
            float kd = ks[nn][d];
#pragma unroll
            for (int j = 0; j < 4; j++) acc[j] += kd * vs[nn][e0 + j];
        }
        __syncthreads();
    }
#pragma unroll
    for (int j = 0; j < 4; j++) sm[d][e0 + j] = acc[j];
    __syncthreads();
    if (tid < 32) {
        float mx = -1e30f;
#pragma unroll
        for (int e = 0; e < 32; e++) mx = fmaxf(mx, sm[tid][e]);
        float ssum = 0.f;
        float ex[32];
#pragma unroll
        for (int e = 0; e < 32; e++) { ex[e] = expf(sm[tid][e] - mx); ssum += ex[e]; }
        float inv = 1.f / ssum;
        float* arow = attn + ((size_t)bh * 32 + tid) * 32;
#pragma unroll
        for (int e = 0; e < 32; e++) arow[e] = ex[e] * inv;
    }
}

// ---------------- apply attention v2: attn row in registers, 8-token staged chunks -----
__global__ __launch_bounds__(384) void apply_attn_k(
    const bf16* __restrict__ qkv, const float* __restrict__ attn,
    bf16* __restrict__ out)
{
    int b = blockIdx.x;
    int chunk = blockIdx.y;            // 14 chunks of 56 tokens
    int tid = threadIdx.x;             // 0..383
    int h = tid >> 5;
    __shared__ float qs[8][CDIM];
    float at[32];
    const float4* ap = (const float4*)(attn + ((size_t)(b * NHEADS) * 32 + tid) * 32);
#pragma unroll
    for (int e4 = 0; e4 < 8; e4++) {
        float4 v = ap[e4];
        at[e4 * 4 + 0] = v.x; at[e4 * 4 + 1] = v.y;
        at[e4 * 4 + 2] = v.z; at[e4 * 4 + 3] = v.w;
    }
    int nbase = chunk * 56;
    for (int t0 = 0; t0 < 56; t0 += 8) {
        __syncthreads();
#pragma unroll
        for (int i = 0; i < 8; i++) {
            int n = nbase + t0 + i;
            qs[i][tid] = __bfloat162float(qkv[((size_t)b * NTOK + n) * (3 * CDIM) + tid]);
        }
        __syncthreads();
#pragma unroll
        for (int i = 0; i < 8; i++) {
            const float* qrow = &qs[i][h * 32];
            float s = 0.f;
#pragma unroll
            for (int e = 0; e < 32; e++) s += at[e] * qrow[e];
            int n = nbase + t0 + i;
            out[((size_t)b * NTOK + n) * CDIM + tid] = __float2bfloat16(s);
        }
    }
}

// ---------------- final transpose: (B,N,C) -> (B,C,H,W) ----------------
__global__ __launch_bounds__(256) void transpose_out(
    const float* __restrict__ in, float* __restrict__ out)
{
    __shared__ float t[32][33];
    int b = blockIdx.z;
    int n0 = blockIdx.y * 32;
    int c0 = blockIdx.x * 32;
    int tx = threadIdx.x, ty = threadIdx.y;   // 32 x 8
    for (int i = ty; i < 32; i += 8) {
        int n = n0 + i;
        if (n < NTOK) t[i][tx] = in[((size_t)b * NTOK + n) * CDIM + c0 + tx];
    }
    __syncthreads();
    for (int i = ty; i < 32; i += 8) {
        int c = c0 + i;
        int n = n0 + tx;
        if (n < NTOK) out[((size_t)b * CDIM + c) * NTOK + n] = t[tx][i];
    }
}

extern "C" void kernel_launch(void* const* d_in, const int* in_sizes, int n_in,
                              void* d_out, int out_size, void* d_ws, size_t ws_size,
                              hipStream_t stream) {
    const float* x      = (const float*)d_in[0];
    const float* cpe1_w = (const float*)d_in[1];
    const float* cpe1_b = (const float*)d_in[2];
    const float* n1g    = (const float*)d_in[3];
    const float* n1b    = (const float*)d_in[4];
    const float* qkv_w  = (const float*)d_in[5];
    const float* proj_w = (const float*)d_in[6];
    const float* proj_b = (const float*)d_in[7];
    const float* cpe2_w = (const float*)d_in[8];
    const float* cpe2_b = (const float*)d_in[9];
    const float* n2g    = (const float*)d_in[10];
    const float* n2b    = (const float*)d_in[11];
    const float* fc1_w  = (const float*)d_in[12];
    const float* fc1_b  = (const float*)d_in[13];
    const float* fc2_w  = (const float*)d_in[14];
    const float* fc2_b  = (const float*)d_in[15];

    const size_t A = (size_t)BN * CDIM;        // 9,633,792
    const size_t HA = A / 2;

    // bf16 weights contiguous at front of ws
    bf16* wqkv  = (bf16*)d_ws;                 // 442368
    bf16* wproj = wqkv + 442368;               // 147456
    bf16* wfc1  = wproj + 147456;              // 589824
    bf16* wfc2  = wfc1 + 589824;               // 589824
    float* base = (float*)d_ws + 884736;

    float* xt        = base;                   // [0, A)        residual stream
    bf16*  curb      = (bf16*)(base + A);      // [A, 1.5A)     LN1 out (bf16)
    bf16*  ylnb      = (bf16*)(base + A);      // phase-2 reuse LN2 out (bf16)
    bf16*  qkvb      = (bf16*)(base + A + HA); // [1.5A, 3A)    qkv (bf16, 3A elems)
    float* x3        = base + A + HA;          // phase-2 reuse [1.5A, 2.5A)
    bf16*  h1        = (bf16*)(base + A + HA + A); // [2.5A, 4.5A) fc1 out (bf16)
    float* attnm     = base + 3 * A;           // [3A, +393216)
    bf16*  attn_outb = (bf16*)(base + 3 * A + 393216);
    float* finalb    = base;                   // xt region reuse
    float* xconv     = base + (A * 7) / 2;     // [3.5A, 4.5A)  dwconv1 NCHW temp
    float* cpe2_wt   = base + (A * 9) / 2;     // [4.5A, +3456) transposed taps

    const int G8_3  = 8 * PERXCD2 * 3;         // 312
    const int G8_9  = 8 * PERXCD2 * 9;         // 936
    const int G8_12 = 8 * PERXCD2 * 12;        // 1248

    // 0. weight conversion fp32 -> bf16 (single launch) + cpe2 tap transpose
    f2b4_k<<<1769472 / 256, 256, 0, stream>>>(qkv_w, proj_w, fc1_w, fc2_w, wqkv);
    wtr_k<<<14, 256, 0, stream>>>(cpe2_w, cpe2_wt);

    // 1a. cpe1 + residual in NCHW (coalesced, LDS-planed)
    dwconv_nchw_plane<<<BBATCH * CDIM, 256, 0, stream>>>(x, cpe1_w, cpe1_b, xconv);
    // 1b. transpose (B,C,N) -> (B,N,C)
    transpose_in<<<dim3(CDIM / 32, (NTOK + 31) / 32, BBATCH), dim3(32, 8), 0, stream>>>(
        xconv, xt);
    // 2. LN1 -> bf16
    layernorm_k<bf16><<<BN / 4, 256, 0, stream>>>(xt, n1g, n1b, curb);
    // 3. qkv GEMM (bf16 MFMA, out bf16)
    gemm_mfma8<0, false, bf16, 384><<<G8_9, 512, 0, stream>>>(
        (const short*)curb, (const short*)wqkv, nullptr, nullptr, qkvb, 1152, 9);
    // 4. channel attention matrices + softmax
    attn_k<<<BBATCH * NHEADS, 256, 0, stream>>>(qkvb, attnm);
    // 5. apply attention to q (out bf16)
    apply_attn_k<<<dim3(BBATCH, 14), 384, 0, stream>>>(qkvb, attnm, attn_outb);
    // 6. proj GEMM + bias + residual (in-place into xt)
    gemm_mfma8<0, true, float, 384><<<G8_3, 512, 0, stream>>>(
        (const short*)attn_outb, (const short*)wproj, proj_b, xt, xt, 384, 3);
    // 7. cpe2 + residual in (B,N,C)  — XCD-swizzled, float4
    dwconv_bnc_v2<<<(BN * 96) / 256, 256, 0, stream>>>(xt, cpe2_wt, cpe2_b, x3);
    // 8. LN2 -> bf16
    layernorm_k<bf16><<<BN / 4, 256, 0, stream>>>(x3, n2g, n2b, ylnb);
    // 9. fc1 + bias + GELU (out bf16)
    gemm_mfma8<1, false, bf16, 384><<<G8_12, 512, 0, stream>>>(
        (const short*)ylnb, (const short*)wfc1, fc1_b, nullptr, h1, 1536, 12);
    // 10. fc2 + bias + residual(x3)
    gemm_mfma8<0, true, float, 1536><<<G8_3, 512, 0, stream>>>(
        (const short*)h1, (const short*)wfc2, fc2_b, x3, finalb, 384, 3);
    // 11. (B,N,C) -> (B,C,H,W)
    transpose_out<<<dim3(CDIM / 32, (NTOK + 31) / 32, BBATCH), dim3(32, 8), 0, stream>>>(
        finalb, (float*)d_out);
}

// Round 5
// 438.508 us; speedup vs baseline: 1.2582x; 1.1091x over previous
//
#include <hip/hip_runtime.h>
#include <hip/hip_bf16.h>

#define CDIM 384
#define NHEADS 12
#define HDIM 32
#define HIDDEN 1536
#define BBATCH 32
#define HH 28
#define WW 28
#define NTOK 784
#define BN (BBATCH * NTOK)   // 25088
#define LN_EPS 1e-5f
#define ATT_SCALE 0.17677669529663687f
#define YTILES 196           // BN / 128
#define PERXCD 25            // ceil(YTILES / 8)

typedef __hip_bfloat16 bf16;
typedef __attribute__((ext_vector_type(8))) short bf16x8;
typedef __attribute__((ext_vector_type(4))) float f32x4;

__device__ __forceinline__ void stf(float* p, float v) { *p = v; }
__device__ __forceinline__ void stf(bf16* p, float v) { *p = __float2bfloat16(v); }

__device__ __forceinline__ short f2bs(float v) {
    bf16 t = __float2bfloat16(v);
    return *reinterpret_cast<short*>(&t);
}

// tanh-form GELU via sigmoid; max |diff| vs exact ~3e-4, well inside tolerance.
__device__ __forceinline__ float gelu_f(float x) {
    float u = x * (0.7978845608f + 0.0356774081f * x * x);
    float e = __expf(-2.f * u);
    return x / (1.f + e);
}

__device__ __forceinline__ void gload16(const void* g, void* l) {
    __builtin_amdgcn_global_load_lds(
        (const __attribute__((address_space(1))) unsigned int*)g,
        (__attribute__((address_space(3))) unsigned int*)l, 16, 0, 0);
}

// ---------------- fp32 -> bf16 weight conversion + cpe2 tap transpose, one launch ------
__global__ __launch_bounds__(256) void prep_k(
    const float* __restrict__ w0, const float* __restrict__ w1,
    const float* __restrict__ w2, const float* __restrict__ w3,
    bf16* __restrict__ dst, const float* __restrict__ cw,
    float* __restrict__ cwt)
{
    int blk = blockIdx.x;
    if (blk >= 6912) {                         // tail blocks: cpe2 (C,9)->(9,C)
        int i = (blk - 6912) * 256 + threadIdx.x;
        if (i < 9 * CDIM) {
            int k = i / CDIM, c = i % CDIM;
            cwt[i] = cw[c * 9 + k];
        }
        return;
    }
    int i = blk * 256 + threadIdx.x;           // 0..1769471, dst regions contiguous
    const float* src; int off;
    if (i < 442368)       { src = w0; off = i; }
    else if (i < 589824)  { src = w1; off = i - 442368; }
    else if (i < 1179648) { src = w2; off = i - 589824; }
    else                  { src = w3; off = i - 1179648; }
    dst[i] = __float2bfloat16(src[off]);
}

// ---------------- dwconv1 pass A: per-(b,c) plane conv in NCHW, coalesced ----------------
__global__ __launch_bounds__(256) void dwconv_nchw_plane(
    const float* __restrict__ x, const float* __restrict__ w,
    const float* __restrict__ bias, float* __restrict__ y)
{
    __shared__ float sm[NTOK];
    int bc = blockIdx.x;                    // b*CDIM + c
    int c = bc % CDIM;
    const float* xp = x + (size_t)bc * NTOK;
    int tid = threadIdx.x;
#pragma unroll
    for (int i = 0; i < 4; i++) {
        int p = tid + i * 256;
        if (p < NTOK) sm[p] = xp[p];
    }
    __syncthreads();
    const float* wp = w + c * 9;
    float w00 = wp[0], w01 = wp[1], w02 = wp[2];
    float w10 = wp[3], w11 = wp[4], w12 = wp[5];
    float w20 = wp[6], w21 = wp[7], w22 = wp[8];
    float bc_ = bias[c];
    float* yp = y + (size_t)bc * NTOK;
#pragma unroll
    for (int i = 0; i < 4; i++) {
        int p = tid + i * 256;
        if (p >= NTOK) break;
        int h = p / WW, wcol = p % WW;
        bool hm = h > 0, hp = h < HH - 1, wm = wcol > 0, wpv = wcol < WW - 1;
        float s = w11 * sm[p];
        if (hm)        s += w01 * sm[p - WW];
        if (hp)        s += w21 * sm[p + WW];
        if (wm)        s += w10 * sm[p - 1];
        if (wpv)       s += w12 * sm[p + 1];
        if (hm && wm)  s += w00 * sm[p - WW - 1];
        if (hm && wpv) s += w02 * sm[p - WW + 1];
        if (hp && wm)  s += w20 * sm[p + WW - 1];
        if (hp && wpv) s += w22 * sm[p + WW + 1];
        yp[p] = sm[p] + s + bc_;
    }
}

// ---------------- dwconv1 pass B: transpose (B,C,N) -> (B,N,C) ----------------
__global__ __launch_bounds__(256) void transpose_in(
    const float* __restrict__ in, float* __restrict__ out)
{
    __shared__ float t[32][33];
    int b = blockIdx.z;
    int n0 = blockIdx.y * 32;
    int c0 = blockIdx.x * 32;
    int tx = threadIdx.x, ty = threadIdx.y;   // 32 x 8
    for (int i = ty; i < 32; i += 8) {
        int n = n0 + tx;
        if (n < NTOK) t[i][tx] = in[((size_t)b * CDIM + c0 + i) * NTOK + n];
    }
    __syncthreads();
    for (int i = ty; i < 32; i += 8) {
        int n = n0 + i;
        if (n < NTOK) out[((size_t)b * NTOK + n) * CDIM + c0 + tx] = t[tx][i];
    }
}

// ---------------- LayerNorm over C=384, one wave per token ----------
template <typename TO>
__global__ __launch_bounds__(256) void layernorm_k(
    const float* __restrict__ in, const float* __restrict__ g,
    const float* __restrict__ b, TO* __restrict__ out)
{
    int wid = threadIdx.x >> 6;
    int lane = threadIdx.x & 63;
    size_t r = (size_t)blockIdx.x * 4 + wid;
    const float* row = in + r * CDIM;
    float v[6];
    float s = 0.f;
#pragma unroll
    for (int j = 0; j < 6; j++) { v[j] = row[lane + 64 * j]; s += v[j]; }
#pragma unroll
    for (int off = 32; off >= 1; off >>= 1) s += __shfl_xor(s, off);
    float mu = s * (1.f / CDIM);
    float q = 0.f;
#pragma unroll
    for (int j = 0; j < 6; j++) { float d = v[j] - mu; q += d * d; }
#pragma unroll
    for (int off = 32; off >= 1; off >>= 1) q += __shfl_xor(q, off);
    float rs = rsqrtf(q * (1.f / CDIM) + LN_EPS);
    TO* orow = out + r * CDIM;
#pragma unroll
    for (int j = 0; j < 6; j++) {
        int c = lane + 64 * j;
        stf(&orow[c], (v[j] - mu) * rs * g[c] + b[c]);
    }
}

// ---------------- fused cpe2 + residual + LN2: one wave per token ----------------------
// Replaces dwconv_bnc_v2 + layernorm_k (removes a full 58MB read/write pass).
// Wave w handles token t: reads 9 neighbor rows (coalesced 1536B each, L2-hot),
// conv taps from LDS weight table, residual+bias, LN via shfl; writes x3 (fp32,
// fc2 residual) and ylnb (bf16, fc1 input).
__global__ __launch_bounds__(256) void cpe2_ln_fused(
    const float* __restrict__ xin, const float* __restrict__ wt,
    const float* __restrict__ cbias, const float* __restrict__ g,
    const float* __restrict__ b, float* __restrict__ x3,
    bf16* __restrict__ lnout)
{
    __shared__ float wts[9 * CDIM];
    int tid = threadIdx.x;
    for (int i = tid; i < 9 * CDIM; i += 256) wts[i] = wt[i];
    __syncthreads();
    int wid = tid >> 6, lane = tid & 63;
    int tok = blockIdx.x * 4 + wid;
    int n = tok % NTOK;
    int h = n / WW, w = n % WW;
    bool hm = h > 0, hp = h < HH - 1, wm = w > 0, wpv = w < WW - 1;
    const float* row = xin + (size_t)tok * CDIM;
    float ctr[6], acc6[6], val[6];
#pragma unroll
    for (int j = 0; j < 6; j++) {
        int c = lane + 64 * j;
        ctr[j] = row[c];
        acc6[j] = wts[4 * CDIM + c] * ctr[j];
    }
#define TAP(k, cond, dn)                                                      \
    if (cond) {                                                               \
        const float* rp = row + (dn) * CDIM;                                  \
        _Pragma("unroll")                                                     \
        for (int j = 0; j < 6; j++) {                                         \
            int c = lane + 64 * j;                                            \
            acc6[j] = fmaf(wts[(k) * CDIM + c], rp[c], acc6[j]);              \
        }                                                                     \
    }
    TAP(0, hm && wm,   -WW - 1)
    TAP(1, hm,         -WW)
    TAP(2, hm && wpv,  -WW + 1)
    TAP(3, wm,         -1)
    TAP(5, wpv,        1)
    TAP(6, hp && wm,   WW - 1)
    TAP(7, hp,         WW)
    TAP(8, hp && wpv,  WW + 1)
#undef TAP
    float s = 0.f;
    float* x3row = x3 + (size_t)tok * CDIM;
#pragma unroll
    for (int j = 0; j < 6; j++) {
        int c = lane + 64 * j;
        val[j] = ctr[j] + acc6[j] + cbias[c];
        x3row[c] = val[j];
        s += val[j];
    }
#pragma unroll
    for (int off = 32; off >= 1; off >>= 1) s += __shfl_xor(s, off);
    float mu = s * (1.f / CDIM);
    float q = 0.f;
#pragma unroll
    for (int j = 0; j < 6; j++) { float d = val[j] - mu; q += d * d; }
#pragma unroll
    for (int off = 32; off >= 1; off >>= 1) q += __shfl_xor(q, off);
    float rs = rsqrtf(q * (1.f / CDIM) + LN_EPS);
    bf16* orow = lnout + (size_t)tok * CDIM;
#pragma unroll
    for (int j = 0; j < 6; j++) {
        int c = lane + 64 * j;
        orow[c] = __float2bfloat16((val[j] - mu) * rs * g[c] + b[c]);
    }
}

// ---------------- MFMA GEMM v8: v4 structure (best measured) + v5 conflict-free swizzle
// 128x128 tile, 4 waves, BK=32, 2-buf, 33KB LDS -> 4 blocks/CU; compile-time K.
// Swizzle (measured 0 conflicts, r2): LDS (row R, group g) holds src colgroup
// g^((R>>1)&3); read slot = quad^((lr>>1)&3). OUTT variant: fc2 writes output
// directly transposed to (B,C,H,W) via two 128x66-fp32 LDS passes (fits the 33792B
// slab exactly; 784%16==0 so stores never straddle a batch boundary).
template <int ACT, bool RES, typename TO, bool OUTT, int K>
__global__ __launch_bounds__(256, 4) void gemm_mfma(
    const short* __restrict__ Abf, const short* __restrict__ Bw,
    const float* __restrict__ bias, const float* __restrict__ res,
    TO* __restrict__ Co, int M, int NX)
{
    int id = blockIdx.x;
    int xcd = id & 7, slot_ = id >> 3;
    int yloc = slot_ / NX, xx = slot_ - yloc * NX;
    int y = xcd * PERXCD + yloc;
    if (y >= YTILES) return;

    __shared__ __align__(16) short lds[16896];  // 33792B: 2 x (A 8K | B 8K) bytes
    const int tid = threadIdx.x;
    const int wid = tid >> 6, lane = tid & 63;
    const int wrow = wid >> 1, wcol = wid & 1;
    const int quad = lane >> 4, lr = lane & 15;
    const int r0 = y * 128, m0 = xx * 128;

    const int srow = lane >> 2;                      // 16 rows per staging round
    const int sg   = (lane & 3) ^ ((lane >> 3) & 3); // source colgroup g^((row>>1)&3)
    const short* gA = Abf + (size_t)(r0 + wid * 32 + srow) * K + sg * 8;
    const short* gB = Bw  + (size_t)(m0 + wid * 32 + srow) * K + sg * 8;

    auto stage = [&](int k0, int p) {
        short* lA = lds + p * 8192 + wid * 1024;
        short* lB = lds + p * 8192 + 4096 + wid * 1024;
#pragma unroll
        for (int k = 0; k < 2; k++) {
            gload16(gA + k0 + (size_t)k * 16 * K, lA + k * 512);
            gload16(gB + k0 + (size_t)k * 16 * K, lB + k * 512);
        }
    };

    const int slot = (quad ^ ((lr >> 1) & 3)) * 8;   // inverse swizzle
    int fA[4], fB[4];
#pragma unroll
    for (int i = 0; i < 4; i++) {
        fA[i] = (wrow * 64 + i * 16 + lr) * 32 + slot;
        fB[i] = 4096 + (wcol * 64 + i * 16 + lr) * 32 + slot;
    }

    f32x4 acc[4][4] = {};

    stage(0, 0);
    int p = 0;
    for (int k0 = 0; k0 < K; k0 += 32) {
        __syncthreads();
        if (k0 + 32 < K) stage(k0 + 32, p ^ 1);     // overlaps compute below
        const short* As = lds + p * 8192;
        bf16x8 av[4], bv[4];
#pragma unroll
        for (int i = 0; i < 4; i++) {
            av[i] = *(const bf16x8*)(As + fA[i]);
            bv[i] = *(const bf16x8*)(As + fB[i]);
        }
#pragma unroll
        for (int i = 0; i < 4; i++)
#pragma unroll
            for (int j = 0; j < 4; j++)
                acc[i][j] = __builtin_amdgcn_mfma_f32_16x16x32_bf16(
                    av[i], bv[j], acc[i][j], 0, 0, 0);
        p ^= 1;
    }

    if constexpr (OUTT) {
        // fp32 output transposed to (B,C,HW): two passes of 64 cols via LDS
        float* Csf = (float*)lds;                   // [128][66] fp32 = 33792B
        __syncthreads();                            // all K-loop LDS reads done
#pragma unroll
        for (int pass = 0; pass < 2; pass++) {
            if (wcol == pass) {
#pragma unroll
                for (int i = 0; i < 4; i++) {
                    int lrow = wrow * 64 + i * 16 + quad * 4;
#pragma unroll
                    for (int j = 0; j < 4; j++) {
                        int lcol = j * 16 + lr;
                        int gc = m0 + pass * 64 + lcol;
                        float bb = bias ? bias[gc] : 0.f;
#pragma unroll
                        for (int rr = 0; rr < 4; rr++) {
                            float v = acc[i][j][rr] + bb;
                            if (RES)
                                v += res[(size_t)(r0 + lrow + rr) * M + gc];
                            if (ACT == 1) v = gelu_f(v);
                            Csf[(lrow + rr) * 66 + lcol] = v;
                        }
                    }
                }
            }
            __syncthreads();
            // flush: 64 lanes = 64 consecutive tokens, same channel -> coalesced
            int tok = tid & 127;
            int csel = tid >> 7;
            int gtok = r0 + tok;
            int bb2 = gtok / NTOK;
            int nn2 = gtok - bb2 * NTOK;
#pragma unroll
            for (int s = 0; s < 32; s++) {
                int cl = s * 2 + csel;
                int gcol = m0 + pass * 64 + cl;
                Co[((size_t)bb2 * CDIM + gcol) * NTOK + nn2] = Csf[tok * 66 + cl];
            }
            __syncthreads();
        }
    } else if constexpr (sizeof(TO) == 4) {
#pragma unroll
        for (int i = 0; i < 4; i++) {
            int gr = r0 + wrow * 64 + i * 16 + quad * 4;
#pragma unroll
            for (int j = 0; j < 4; j++) {
                int gc = m0 + wcol * 64 + j * 16 + lr;
                float bb = bias ? bias[gc] : 0.f;
#pragma unroll
                for (int rr = 0; rr < 4; rr++) {
                    size_t idx = (size_t)(gr + rr) * M + gc;
                    float v = acc[i][j][rr] + bb;
                    if (RES) v += res[idx];
                    if (ACT == 1) v = gelu_f(v);
                    stf((float*)&Co[idx], v);
                }
            }
        }
    } else {
        __syncthreads();                  // all LDS reads done before Cs overwrite
        short* Cs = lds;
#pragma unroll
        for (int i = 0; i < 4; i++) {
            int lrow = wrow * 64 + i * 16 + quad * 4;
#pragma unroll
            for (int j = 0; j < 4; j++) {
                int lcol = wcol * 64 + j * 16 + lr;
                float bb = bias ? bias[m0 + lcol] : 0.f;
#pragma unroll
                for (int rr = 0; rr < 4; rr++) {
                    float v = acc[i][j][rr] + bb;
                    if (ACT == 1) v = gelu_f(v);
                    Cs[(lrow + rr) * 132 + lcol] = f2bs(v);
                }
            }
        }
        __syncthreads();
        short* co = (short*)Co;
#pragma unroll
        for (int s = 0; s < 16; s++) {
            int row = s * 8 + (tid >> 5);
            int seg = tid & 31;
            uint2 vv = *(const uint2*)(Cs + row * 132 + seg * 4);
            *(uint2*)(co + (size_t)(r0 + row) * M + m0 + seg * 4) = vv;
        }
    }
}

// ---------------- channel attention: attn[b,h,d,e] = softmax_e(SCALE * sum_n k*v) ------
__global__ __launch_bounds__(256) void attn_k(
    const bf16* __restrict__ qkv, float* __restrict__ attn)
{
    int bh = blockIdx.x;
    int b = bh / NHEADS, h = bh % NHEADS;
    __shared__ float ks[64][32];
    __shared__ float vs[64][32];
    __shared__ float sm[32][33];
    int tid = threadIdx.x;
    int d = tid >> 3, e0 = (tid & 7) * 4;
    float acc[4] = {0.f, 0.f, 0.f, 0.f};
    for (int n0 = 0; n0 < NTOK; n0 += 64) {
#pragma unroll
        for (int i = 0; i < 8; i++) {
            int idx = tid + i * 256;
            int nn = idx >> 5, cc = idx & 31;
            int n = n0 + nn;
            float kv = 0.f, vv = 0.f;
            if (n < NTOK) {
                size_t base = ((size_t)b * NTOK + n) * (3 * CDIM);
                kv = ATT_SCALE * __bfloat162float(qkv[base + CDIM + h * HDIM + cc]);
                vv = __bfloat162float(qkv[base + 2 * CDIM + h * HDIM + cc]);
            }
            ks[nn][cc] = kv; vs[nn][cc] = vv;
        }
        __syncthreads();
#pragma unroll 8
        for (int nn = 0; nn < 64; nn++) {
            float kd = ks[nn][d];
            float4 vv4 = *(const float4*)&vs[nn][e0];
            acc[0] = fmaf(kd, vv4.x, acc[0]);
            acc[1] = fmaf(kd, vv4.y, acc[1]);
            acc[2] = fmaf(kd, vv4.z, acc[2]);
            acc[3] = fmaf(kd, vv4.w, acc[3]);
        }
        __syncthreads();
    }
#pragma unroll
    for (int j = 0; j < 4; j++) sm[d][e0 + j] = acc[j];
    __syncthreads();
    if (tid < 32) {
        float mx = -1e30f;
#pragma unroll
        for (int e = 0; e < 32; e++) mx = fmaxf(mx, sm[tid][e]);
        float ssum = 0.f;
        float ex[32];
#pragma unroll
        for (int e = 0; e < 32; e++) { ex[e] = expf(sm[tid][e] - mx); ssum += ex[e]; }
        float inv = 1.f / ssum;
        float* arow = attn + ((size_t)bh * 32 + tid) * 32;
#pragma unroll
        for (int e = 0; e < 32; e++) arow[e] = ex[e] * inv;
    }
}

// ---------------- apply attention: attn row in registers, 8-token staged chunks --------
__global__ __launch_bounds__(384) void apply_attn_k(
    const bf16* __restrict__ qkv, const float* __restrict__ attn,
    bf16* __restrict__ out)
{
    int b = blockIdx.x;
    int chunk = blockIdx.y;            // 14 chunks of 56 tokens
    int tid = threadIdx.x;             // 0..383
    int h = tid >> 5;
    __shared__ float qs[8][CDIM];
    float at[32];
    const float4* ap = (const float4*)(attn + ((size_t)(b * NHEADS) * 32 + tid) * 32);
#pragma unroll
    for (int e4 = 0; e4 < 8; e4++) {
        float4 v = ap[e4];
        at[e4 * 4 + 0] = v.x; at[e4 * 4 + 1] = v.y;
        at[e4 * 4 + 2] = v.z; at[e4 * 4 + 3] = v.w;
    }
    int nbase = chunk * 56;
    for (int t0 = 0; t0 < 56; t0 += 8) {
        __syncthreads();
#pragma unroll
        for (int i = 0; i < 8; i++) {
            int n = nbase + t0 + i;
            qs[i][tid] = __bfloat162float(qkv[((size_t)b * NTOK + n) * (3 * CDIM) + tid]);
        }
        __syncthreads();
#pragma unroll
        for (int i = 0; i < 8; i++) {
            const float4* q4 = (const float4*)&qs[i][h * 32];
            float s = 0.f;
#pragma unroll
            for (int e4 = 0; e4 < 8; e4++) {
                float4 qv = q4[e4];
                s = fmaf(at[e4 * 4 + 0], qv.x, s);
                s = fmaf(at[e4 * 4 + 1], qv.y, s);
                s = fmaf(at[e4 * 4 + 2], qv.z, s);
                s = fmaf(at[e4 * 4 + 3], qv.w, s);
            }
            int n = nbase + t0 + i;
            out[((size_t)b * NTOK + n) * CDIM + tid] = __float2bfloat16(s);
        }
    }
}

extern "C" void kernel_launch(void* const* d_in, const int* in_sizes, int n_in,
                              void* d_out, int out_size, void* d_ws, size_t ws_size,
                              hipStream_t stream) {
    const float* x      = (const float*)d_in[0];
    const float* cpe1_w = (const float*)d_in[1];
    const float* cpe1_b = (const float*)d_in[2];
    const float* n1g    = (const float*)d_in[3];
    const float* n1b    = (const float*)d_in[4];
    const float* qkv_w  = (const float*)d_in[5];
    const float* proj_w = (const float*)d_in[6];
    const float* proj_b = (const float*)d_in[7];
    const float* cpe2_w = (const float*)d_in[8];
    const float* cpe2_b = (const float*)d_in[9];
    const float* n2g    = (const float*)d_in[10];
    const float* n2b    = (const float*)d_in[11];
    const float* fc1_w  = (const float*)d_in[12];
    const float* fc1_b  = (const float*)d_in[13];
    const float* fc2_w  = (const float*)d_in[14];
    const float* fc2_b  = (const float*)d_in[15];

    const size_t A = (size_t)BN * CDIM;        // 9,633,792
    const size_t HA = A / 2;

    // bf16 weights contiguous at front of ws
    bf16* wqkv  = (bf16*)d_ws;                 // 442368
    bf16* wproj = wqkv + 442368;               // 147456
    bf16* wfc1  = wproj + 147456;              // 589824
    bf16* wfc2  = wfc1 + 589824;               // 589824
    float* base = (float*)d_ws + 884736;

    float* xt        = base;                   // [0, A)        residual stream
    bf16*  curb      = (bf16*)(base + A);      // [A, 1.5A)     LN1 out (bf16)
    bf16*  ylnb      = (bf16*)(base + A);      // phase-2 reuse LN2 out (bf16)
    bf16*  qkvb      = (bf16*)(base + A + HA); // [1.5A, 3A)    qkv (bf16, 3A elems)
    float* x3        = base + A + HA;          // phase-2 reuse [1.5A, 2.5A)
    bf16*  h1        = (bf16*)(base + A + HA + A); // [2.5A, 4.5A) fc1 out (bf16)
    float* attnm     = base + 3 * A;           // [3A, +393216)
    bf16*  attn_outb = (bf16*)(base + 3 * A + 393216);
    float* xconv     = base + (A * 7) / 2;     // [3.5A, 4.5A)  dwconv1 NCHW temp
    float* cpe2_wt   = base + (A * 9) / 2;     // [4.5A, +3456) transposed taps

    const int GEMM_GRID3  = 8 * PERXCD * 3;    // 600
    const int GEMM_GRID9  = 8 * PERXCD * 9;    // 1800
    const int GEMM_GRID12 = 8 * PERXCD * 12;   // 2400

    // 0. weight conversion fp32 -> bf16 + cpe2 tap transpose (one launch)
    prep_k<<<6926, 256, 0, stream>>>(qkv_w, proj_w, fc1_w, fc2_w, wqkv,
                                     cpe2_w, cpe2_wt);

    // 1a. cpe1 + residual in NCHW (coalesced, LDS-planed)
    dwconv_nchw_plane<<<BBATCH * CDIM, 256, 0, stream>>>(x, cpe1_w, cpe1_b, xconv);
    // 1b. transpose (B,C,N) -> (B,N,C)
    transpose_in<<<dim3(CDIM / 32, (NTOK + 31) / 32, BBATCH), dim3(32, 8), 0, stream>>>(
        xconv, xt);
    // 2. LN1 -> bf16
    layernorm_k<bf16><<<BN / 4, 256, 0, stream>>>(xt, n1g, n1b, curb);
    // 3. qkv GEMM (bf16 MFMA, out bf16)
    gemm_mfma<0, false, bf16, false, 384><<<GEMM_GRID9, 256, 0, stream>>>(
        (const short*)curb, (const short*)wqkv, nullptr, nullptr, qkvb, 1152, 9);
    // 4. channel attention matrices + softmax
    attn_k<<<BBATCH * NHEADS, 256, 0, stream>>>(qkvb, attnm);
    // 5. apply attention to q (out bf16)
    apply_attn_k<<<dim3(BBATCH, 14), 384, 0, stream>>>(qkvb, attnm, attn_outb);
    // 6. proj GEMM + bias + residual (in-place into xt)
    gemm_mfma<0, true, float, false, 384><<<GEMM_GRID3, 256, 0, stream>>>(
        (const short*)attn_outb, (const short*)wproj, proj_b, xt, xt, 384, 3);
    // 7+8. fused cpe2 + residual + LN2 (writes x3 fp32 and ylnb bf16)
    cpe2_ln_fused<<<BN / 4, 256, 0, stream>>>(xt, cpe2_wt, cpe2_b, n2g, n2b,
                                              x3, ylnb);
    // 9. fc1 + bias + GELU (out bf16)
    gemm_mfma<1, false, bf16, false, 384><<<GEMM_GRID12, 256, 0, stream>>>(
        (const short*)ylnb, (const short*)wfc1, fc1_b, nullptr, h1, 1536, 12);
    // 10. fc2 + bias + residual(x3), output directly transposed to (B,C,H,W)
    gemm_mfma<0, true, float, true, 1536><<<GEMM_GRID3, 256, 0, stream>>>(
        (const short*)h1, (const short*)wfc2, fc2_b, x3, (float*)d_out, 384, 3);
}

// Round 6
// 434.232 us; speedup vs baseline: 1.2706x; 1.0098x over previous
//
#include <hip/hip_runtime.h>
#include <hip/hip_bf16.h>

#define CDIM 384
#define NHEADS 12
#define HDIM 32
#define HIDDEN 1536
#define BBATCH 32
#define HH 28
#define WW 28
#define NTOK 784
#define BN (BBATCH * NTOK)   // 25088
#define LN_EPS 1e-5f
#define ATT_SCALE 0.17677669529663687f
#define YTILES 196           // BN / 128
#define PERXCD 25            // ceil(YTILES / 8)

typedef __hip_bfloat16 bf16;
typedef __attribute__((ext_vector_type(8))) short bf16x8;
typedef __attribute__((ext_vector_type(4))) float f32x4;

__device__ __forceinline__ void stf(float* p, float v) { *p = v; }
__device__ __forceinline__ void stf(bf16* p, float v) { *p = __float2bfloat16(v); }

__device__ __forceinline__ short f2bs(float v) {
    bf16 t = __float2bfloat16(v);
    return *reinterpret_cast<short*>(&t);
}

__device__ __forceinline__ float bf2f(unsigned short u) {
    return __uint_as_float(((unsigned)u) << 16);
}

// tanh-form GELU via sigmoid; max |diff| vs exact ~3e-4, well inside tolerance.
__device__ __forceinline__ float gelu_f(float x) {
    float u = x * (0.7978845608f + 0.0356774081f * x * x);
    float e = __expf(-2.f * u);
    return x / (1.f + e);
}

__device__ __forceinline__ void gload16(const void* g, void* l) {
    __builtin_amdgcn_global_load_lds(
        (const __attribute__((address_space(1))) unsigned int*)g,
        (__attribute__((address_space(3))) unsigned int*)l, 16, 0, 0);
}

// ---------------- fp32 -> bf16 weight conversion + cpe2 tap transpose, one launch ------
__global__ __launch_bounds__(256) void prep_k(
    const float* __restrict__ w0, const float* __restrict__ w1,
    const float* __restrict__ w2, const float* __restrict__ w3,
    bf16* __restrict__ dst, const float* __restrict__ cw,
    float* __restrict__ cwt)
{
    int blk = blockIdx.x;
    if (blk >= 6912) {                         // tail blocks: cpe2 (C,9)->(9,C)
        int i = (blk - 6912) * 256 + threadIdx.x;
        if (i < 9 * CDIM) {
            int k = i / CDIM, c = i % CDIM;
            cwt[i] = cw[c * 9 + k];
        }
        return;
    }
    int i = blk * 256 + threadIdx.x;           // 0..1769471, dst regions contiguous
    const float* src; int off;
    if (i < 442368)       { src = w0; off = i; }
    else if (i < 589824)  { src = w1; off = i - 442368; }
    else if (i < 1179648) { src = w2; off = i - 589824; }
    else                  { src = w3; off = i - 1179648; }
    dst[i] = __float2bfloat16(src[off]);
}

// ---------------- fused cpe1 + residual + transpose: (B,C,N) in -> (B,N,C) out ---------
// Replaces dwconv_nchw_plane + transpose_in (deletes the 77MB xconv round-trip).
// Block = 32c x 32n tile; conv read window = 96 tokens (n0-32 .. n0+63) per c-row,
// staged coalesced; conv computed in NCHW index space; transposed via LDS tile.
__global__ __launch_bounds__(256) void cpe1_tr_fused(
    const float* __restrict__ x, const float* __restrict__ w,
    const float* __restrict__ bias, float* __restrict__ xt)
{
    __shared__ float sm[32][100];   // 32 c-rows x 96-token window (+4 pad)
    __shared__ float t[32][33];     // transposed out tile [n][c]
    int b = blockIdx.z;
    int n0 = blockIdx.y * 32;
    int c0 = blockIdx.x * 32;
    int tx = threadIdx.x, ty = threadIdx.y;  // 32 x 8
    int wstart = n0 - 32;
    for (int ci = ty; ci < 32; ci += 8) {
        const float* bp = x + ((size_t)b * CDIM + c0 + ci) * NTOK;
#pragma unroll
        for (int j = 0; j < 3; j++) {
            int l = tx + j * 32;
            int n = wstart + l;
            sm[ci][l] = ((unsigned)n < NTOK) ? bp[n] : 0.f;
        }
    }
    __syncthreads();
    int n = n0 + tx;
    if (n < NTOK) {
        int h = n / WW, wc = n % WW;
        bool hm = h > 0, hp = h < HH - 1, wm = wc > 0, wpv = wc < WW - 1;
        int l = tx + 32;
        for (int ci = ty; ci < 32; ci += 8) {
            const float* wp = w + (c0 + ci) * 9;     // uniform across lanes -> scalar
            float s = wp[4] * sm[ci][l];
            if (hm)        s += wp[1] * sm[ci][l - WW];
            if (hp)        s += wp[7] * sm[ci][l + WW];
            if (wm)        s += wp[3] * sm[ci][l - 1];
            if (wpv)       s += wp[5] * sm[ci][l + 1];
            if (hm && wm)  s += wp[0] * sm[ci][l - WW - 1];
            if (hm && wpv) s += wp[2] * sm[ci][l - WW + 1];
            if (hp && wm)  s += wp[6] * sm[ci][l + WW - 1];
            if (hp && wpv) s += wp[8] * sm[ci][l + WW + 1];
            t[tx][ci] = sm[ci][l] + s + bias[c0 + ci];
        }
    }
    __syncthreads();
    for (int i = ty; i < 32; i += 8) {
        int nn = n0 + i;
        if (nn < NTOK)
            xt[((size_t)b * NTOK + nn) * CDIM + c0 + tx] = t[i][tx];
    }
}

// ---------------- LN1: 32 lanes per token, float4 loads, ushort4 bf16 stores -----------
__global__ __launch_bounds__(256) void ln1_k(
    const float* __restrict__ in, const float* __restrict__ g,
    const float* __restrict__ b, bf16* __restrict__ out)
{
    int tid = threadIdx.x;
    int l = tid & 31;
    size_t tok = (size_t)blockIdx.x * 8 + (tid >> 5);
    const float4* row = (const float4*)(in + tok * CDIM);
    float4 v[3];
    float s = 0.f;
#pragma unroll
    for (int j = 0; j < 3; j++) {
        v[j] = row[l + j * 32];
        s += v[j].x + v[j].y + v[j].z + v[j].w;
    }
#pragma unroll
    for (int off = 16; off >= 1; off >>= 1) s += __shfl_xor(s, off);
    float mu = s * (1.f / CDIM);
    float q = 0.f;
#pragma unroll
    for (int j = 0; j < 3; j++) {
        float dx = v[j].x - mu, dy = v[j].y - mu;
        float dz = v[j].z - mu, dw = v[j].w - mu;
        q += dx * dx + dy * dy + dz * dz + dw * dw;
    }
#pragma unroll
    for (int off = 16; off >= 1; off >>= 1) q += __shfl_xor(q, off);
    float rs = rsqrtf(q * (1.f / CDIM) + LN_EPS);
    const float4* g4 = (const float4*)g;
    const float4* b4 = (const float4*)b;
    ushort4* o4 = (ushort4*)(out + tok * CDIM);
#pragma unroll
    for (int j = 0; j < 3; j++) {
        int idx = l + j * 32;
        float4 gv = g4[idx], bv = b4[idx];
        ushort4 r;
        r.x = (unsigned short)f2bs((v[j].x - mu) * rs * gv.x + bv.x);
        r.y = (unsigned short)f2bs((v[j].y - mu) * rs * gv.y + bv.y);
        r.z = (unsigned short)f2bs((v[j].z - mu) * rs * gv.z + bv.z);
        r.w = (unsigned short)f2bs((v[j].w - mu) * rs * gv.w + bv.w);
        o4[idx] = r;
    }
}

// ---------------- fused cpe2 + residual + LN2: 32 lanes per token, float4 --------------
__global__ __launch_bounds__(256) void cpe2_ln_fused(
    const float* __restrict__ xin, const float* __restrict__ wt,
    const float* __restrict__ cbias, const float* __restrict__ g,
    const float* __restrict__ b, float* __restrict__ x3,
    bf16* __restrict__ lnout)
{
    __shared__ float wts[9 * CDIM];
    int tid = threadIdx.x;
    for (int i = tid; i < 864; i += 256)
        ((float4*)wts)[i] = ((const float4*)wt)[i];
    __syncthreads();
    int l = tid & 31;
    size_t tok = (size_t)blockIdx.x * 8 + (tid >> 5);
    int n = (int)(tok % NTOK);
    int h = n / WW, wc = n % WW;
    bool hm = h > 0, hp = h < HH - 1, wm = wc > 0, wpv = wc < WW - 1;
    const float* row = xin + tok * CDIM;
    const float4* w4 = (const float4*)wts;
    float4 ctr[3], acc[3];
#pragma unroll
    for (int j = 0; j < 3; j++) {
        int idx = l + j * 32;
        ctr[j] = ((const float4*)row)[idx];
        float4 ww = w4[4 * 96 + idx];
        acc[j].x = ww.x * ctr[j].x; acc[j].y = ww.y * ctr[j].y;
        acc[j].z = ww.z * ctr[j].z; acc[j].w = ww.w * ctr[j].w;
    }
#define TAP(k, cond, dn)                                                     \
    if (cond) {                                                              \
        const float4* rp = (const float4*)(row + (dn) * CDIM);               \
        _Pragma("unroll")                                                    \
        for (int j = 0; j < 3; j++) {                                        \
            int idx = l + j * 32;                                            \
            float4 vv = rp[idx];                                             \
            float4 ww = w4[(k) * 96 + idx];                                  \
            acc[j].x = fmaf(ww.x, vv.x, acc[j].x);                           \
            acc[j].y = fmaf(ww.y, vv.y, acc[j].y);                           \
            acc[j].z = fmaf(ww.z, vv.z, acc[j].z);                           \
            acc[j].w = fmaf(ww.w, vv.w, acc[j].w);                           \
        }                                                                    \
    }
    TAP(0, hm && wm,   -WW - 1)
    TAP(1, hm,         -WW)
    TAP(2, hm && wpv,  -WW + 1)
    TAP(3, wm,         -1)
    TAP(5, wpv,        1)
    TAP(6, hp && wm,   WW - 1)
    TAP(7, hp,         WW)
    TAP(8, hp && wpv,  WW + 1)
#undef TAP
    float s = 0.f;
    float4 val[3];
    float4* x3r = (float4*)(x3 + tok * CDIM);
#pragma unroll
    for (int j = 0; j < 3; j++) {
        int idx = l + j * 32;
        float4 cb = ((const float4*)cbias)[idx];
        val[j].x = ctr[j].x + acc[j].x + cb.x;
        val[j].y = ctr[j].y + acc[j].y + cb.y;
        val[j].z = ctr[j].z + acc[j].z + cb.z;
        val[j].w = ctr[j].w + acc[j].w + cb.w;
        x3r[idx] = val[j];
        s += val[j].x + val[j].y + val[j].z + val[j].w;
    }
#pragma unroll
    for (int off = 16; off >= 1; off >>= 1) s += __shfl_xor(s, off);
    float mu = s * (1.f / CDIM);
    float q = 0.f;
#pragma unroll
    for (int j = 0; j < 3; j++) {
        float dx = val[j].x - mu, dy = val[j].y - mu;
        float dz = val[j].z - mu, dw = val[j].w - mu;
        q += dx * dx + dy * dy + dz * dz + dw * dw;
    }
#pragma unroll
    for (int off = 16; off >= 1; off >>= 1) q += __shfl_xor(q, off);
    float rs = rsqrtf(q * (1.f / CDIM) + LN_EPS);
    const float4* g4 = (const float4*)g;
    const float4* b4 = (const float4*)b;
    ushort4* o4 = (ushort4*)(lnout + tok * CDIM);
#pragma unroll
    for (int j = 0; j < 3; j++) {
        int idx = l + j * 32;
        float4 gv = g4[idx], bv = b4[idx];
        ushort4 r;
        r.x = (unsigned short)f2bs((val[j].x - mu) * rs * gv.x + bv.x);
        r.y = (unsigned short)f2bs((val[j].y - mu) * rs * gv.y + bv.y);
        r.z = (unsigned short)f2bs((val[j].z - mu) * rs * gv.z + bv.z);
        r.w = (unsigned short)f2bs((val[j].w - mu) * rs * gv.w + bv.w);
        o4[idx] = r;
    }
}

// ---------------- MFMA GEMM v8: v4 structure (best measured) + v5 conflict-free swizzle
// 128x128 tile, 4 waves, BK=32, 2-buf, 33KB LDS -> 4 blocks/CU; compile-time K.
// Swizzle (measured 0 conflicts, r2): LDS (row R, group g) holds src colgroup
// g^((R>>1)&3); read slot = quad^((lr>>1)&3). OUTT variant: fc2 writes output
// directly transposed to (B,C,H,W) via two 128x66-fp32 LDS passes.
template <int ACT, bool RES, typename TO, bool OUTT, int K>
__global__ __launch_bounds__(256, 4) void gemm_mfma(
    const short* __restrict__ Abf, const short* __restrict__ Bw,
    const float* __restrict__ bias, const float* __restrict__ res,
    TO* __restrict__ Co, int M, int NX)
{
    int id = blockIdx.x;
    int xcd = id & 7, slot_ = id >> 3;
    int yloc = slot_ / NX, xx = slot_ - yloc * NX;
    int y = xcd * PERXCD + yloc;
    if (y >= YTILES) return;

    __shared__ __align__(16) short lds[16896];  // 33792B: 2 x (A 8K | B 8K) bytes
    const int tid = threadIdx.x;
    const int wid = tid >> 6, lane = tid & 63;
    const int wrow = wid >> 1, wcol = wid & 1;
    const int quad = lane >> 4, lr = lane & 15;
    const int r0 = y * 128, m0 = xx * 128;

    const int srow = lane >> 2;                      // 16 rows per staging round
    const int sg   = (lane & 3) ^ ((lane >> 3) & 3); // source colgroup g^((row>>1)&3)
    const short* gA = Abf + (size_t)(r0 + wid * 32 + srow) * K + sg * 8;
    const short* gB = Bw  + (size_t)(m0 + wid * 32 + srow) * K + sg * 8;

    auto stage = [&](int k0, int p) {
        short* lA = lds + p * 8192 + wid * 1024;
        short* lB = lds + p * 8192 + 4096 + wid * 1024;
#pragma unroll
        for (int k = 0; k < 2; k++) {
            gload16(gA + k0 + (size_t)k * 16 * K, lA + k * 512);
            gload16(gB + k0 + (size_t)k * 16 * K, lB + k * 512);
        }
    };

    const int slot = (quad ^ ((lr >> 1) & 3)) * 8;   // inverse swizzle
    int fA[4], fB[4];
#pragma unroll
    for (int i = 0; i < 4; i++) {
        fA[i] = (wrow * 64 + i * 16 + lr) * 32 + slot;
        fB[i] = 4096 + (wcol * 64 + i * 16 + lr) * 32 + slot;
    }

    f32x4 acc[4][4] = {};

    stage(0, 0);
    int p = 0;
    for (int k0 = 0; k0 < K; k0 += 32) {
        __syncthreads();
        if (k0 + 32 < K) stage(k0 + 32, p ^ 1);     // overlaps compute below
        const short* As = lds + p * 8192;
        bf16x8 av[4], bv[4];
#pragma unroll
        for (int i = 0; i < 4; i++) {
            av[i] = *(const bf16x8*)(As + fA[i]);
            bv[i] = *(const bf16x8*)(As + fB[i]);
        }
#pragma unroll
        for (int i = 0; i < 4; i++)
#pragma unroll
            for (int j = 0; j < 4; j++)
                acc[i][j] = __builtin_amdgcn_mfma_f32_16x16x32_bf16(
                    av[i], bv[j], acc[i][j], 0, 0, 0);
        p ^= 1;
    }

    if constexpr (OUTT) {
        // fp32 output transposed to (B,C,HW): two passes of 64 cols via LDS
        float* Csf = (float*)lds;                   // [128][66] fp32 = 33792B
        __syncthreads();                            // all K-loop LDS reads done
#pragma unroll
        for (int pass = 0; pass < 2; pass++) {
            if (wcol == pass) {
#pragma unroll
                for (int i = 0; i < 4; i++) {
                    int lrow = wrow * 64 + i * 16 + quad * 4;
#pragma unroll
                    for (int j = 0; j < 4; j++) {
                        int lcol = j * 16 + lr;
                        int gc = m0 + pass * 64 + lcol;
                        float bb = bias ? bias[gc] : 0.f;
#pragma unroll
                        for (int rr = 0; rr < 4; rr++) {
                            float v = acc[i][j][rr] + bb;
                            if (RES)
                                v += res[(size_t)(r0 + lrow + rr) * M + gc];
                            if (ACT == 1) v = gelu_f(v);
                            Csf[(lrow + rr) * 66 + lcol] = v;
                        }
                    }
                }
            }
            __syncthreads();
            // flush: 128 lanes = 128 consecutive tokens, same channel -> coalesced
            int tok = tid & 127;
            int csel = tid >> 7;
            int gtok = r0 + tok;
            int bb2 = gtok / NTOK;
            int nn2 = gtok - bb2 * NTOK;
#pragma unroll
            for (int s = 0; s < 32; s++) {
                int cl = s * 2 + csel;
                int gcol = m0 + pass * 64 + cl;
                Co[((size_t)bb2 * CDIM + gcol) * NTOK + nn2] = Csf[tok * 66 + cl];
            }
            __syncthreads();
        }
    } else if constexpr (sizeof(TO) == 4) {
#pragma unroll
        for (int i = 0; i < 4; i++) {
            int gr = r0 + wrow * 64 + i * 16 + quad * 4;
#pragma unroll
            for (int j = 0; j < 4; j++) {
                int gc = m0 + wcol * 64 + j * 16 + lr;
                float bb = bias ? bias[gc] : 0.f;
#pragma unroll
                for (int rr = 0; rr < 4; rr++) {
                    size_t idx = (size_t)(gr + rr) * M + gc;
                    float v = acc[i][j][rr] + bb;
                    if (RES) v += res[idx];
                    if (ACT == 1) v = gelu_f(v);
                    stf((float*)&Co[idx], v);
                }
            }
        }
    } else {
        __syncthreads();                  // all LDS reads done before Cs overwrite
        short* Cs = lds;
#pragma unroll
        for (int i = 0; i < 4; i++) {
            int lrow = wrow * 64 + i * 16 + quad * 4;
#pragma unroll
            for (int j = 0; j < 4; j++) {
                int lcol = wcol * 64 + j * 16 + lr;
                float bb = bias ? bias[m0 + lcol] : 0.f;
#pragma unroll
                for (int rr = 0; rr < 4; rr++) {
                    float v = acc[i][j][rr] + bb;
                    if (ACT == 1) v = gelu_f(v);
                    Cs[(lrow + rr) * 132 + lcol] = f2bs(v);
                }
            }
        }
        __syncthreads();
        short* co = (short*)Co;
#pragma unroll
        for (int s = 0; s < 16; s++) {
            int row = s * 8 + (tid >> 5);
            int seg = tid & 31;
            uint2 vv = *(const uint2*)(Cs + row * 132 + seg * 4);
            *(uint2*)(co + (size_t)(r0 + row) * M + m0 + seg * 4) = vv;
        }
    }
}

// ---------------- channel attention: attn[b,h,d,e] = softmax_e(SCALE * sum_n k*v) ------
// Staging via uint4 (8 bf16 = 16B/lane), float4 LDS stores.
__global__ __launch_bounds__(256) void attn_k(
    const bf16* __restrict__ qkv, float* __restrict__ attn)
{
    int bh = blockIdx.x;
    int b = bh / NHEADS, h = bh % NHEADS;
    __shared__ float ks[64][32];
    __shared__ float vs[64][32];
    __shared__ float sm[32][33];
    int tid = threadIdx.x;
    int d = tid >> 3, e0 = (tid & 7) * 4;
    int nn = tid >> 2, q8 = (tid & 3) * 8;
    float acc[4] = {0.f, 0.f, 0.f, 0.f};
    for (int n0 = 0; n0 < NTOK; n0 += 64) {
        int n = n0 + nn;
        float kv[8], vv[8];
        if (n < NTOK) {
            const unsigned short* base =
                (const unsigned short*)qkv + ((size_t)b * NTOK + n) * (3 * CDIM);
            uint4 kq = *(const uint4*)(base + CDIM + h * HDIM + q8);
            uint4 vq = *(const uint4*)(base + 2 * CDIM + h * HDIM + q8);
            const unsigned short* kp = (const unsigned short*)&kq;
            const unsigned short* vp = (const unsigned short*)&vq;
#pragma unroll
            for (int j = 0; j < 8; j++) {
                kv[j] = ATT_SCALE * bf2f(kp[j]);
                vv[j] = bf2f(vp[j]);
            }
        } else {
#pragma unroll
            for (int j = 0; j < 8; j++) { kv[j] = 0.f; vv[j] = 0.f; }
        }
        *(float4*)&ks[nn][q8]     = make_float4(kv[0], kv[1], kv[2], kv[3]);
        *(float4*)&ks[nn][q8 + 4] = make_float4(kv[4], kv[5], kv[6], kv[7]);
        *(float4*)&vs[nn][q8]     = make_float4(vv[0], vv[1], vv[2], vv[3]);
        *(float4*)&vs[nn][q8 + 4] = make_float4(vv[4], vv[5], vv[6], vv[7]);
        __syncthreads();
#pragma unroll 8
        for (int k = 0; k < 64; k++) {
            float kd = ks[k][d];
            float4 vv4 = *(const float4*)&vs[k][e0];
            acc[0] = fmaf(kd, vv4.x, acc[0]);
            acc[1] = fmaf(kd, vv4.y, acc[1]);
            acc[2] = fmaf(kd, vv4.z, acc[2]);
            acc[3] = fmaf(kd, vv4.w, acc[3]);
        }
        __syncthreads();
    }
#pragma unroll
    for (int j = 0; j < 4; j++) sm[d][e0 + j] = acc[j];
    __syncthreads();
    if (tid < 32) {
        float mx = -1e30f;
#pragma unroll
        for (int e = 0; e < 32; e++) mx = fmaxf(mx, sm[tid][e]);
        float ssum = 0.f;
        float ex[32];
#pragma unroll
        for (int e = 0; e < 32; e++) { ex[e] = expf(sm[tid][e] - mx); ssum += ex[e]; }
        float inv = 1.f / ssum;
        float* arow = attn + ((size_t)bh * 32 + tid) * 32;
#pragma unroll
        for (int e = 0; e < 32; e++) arow[e] = ex[e] * inv;
    }
}

// ---------------- apply attention: uint4 staging, attn row in registers ----------------
__global__ __launch_bounds__(384) void apply_attn_k(
    const bf16* __restrict__ qkv, const float* __restrict__ attn,
    bf16* __restrict__ out)
{
    int b = blockIdx.x;
    int chunk = blockIdx.y;            // 14 chunks of 56 tokens
    int tid = threadIdx.x;             // 0..383
    int h = tid >> 5;
    __shared__ float qs[8][CDIM];
    float at[32];
    const float4* ap = (const float4*)(attn + ((size_t)(b * NHEADS) * 32 + tid) * 32);
#pragma unroll
    for (int e4 = 0; e4 < 8; e4++) {
        float4 v = ap[e4];
        at[e4 * 4 + 0] = v.x; at[e4 * 4 + 1] = v.y;
        at[e4 * 4 + 2] = v.z; at[e4 * 4 + 3] = v.w;
    }
    int row8 = tid / 48;               // 0..7
    int seg = tid - row8 * 48;         // 0..47
    int nbase = chunk * 56;
    for (int t0 = 0; t0 < 56; t0 += 8) {
        __syncthreads();
        {
            int n = nbase + t0 + row8;
            const unsigned short* src =
                (const unsigned short*)qkv + ((size_t)b * NTOK + n) * (3 * CDIM) + seg * 8;
            uint4 qv = *(const uint4*)src;
            const unsigned short* qp = (const unsigned short*)&qv;
            *(float4*)&qs[row8][seg * 8] =
                make_float4(bf2f(qp[0]), bf2f(qp[1]), bf2f(qp[2]), bf2f(qp[3]));
            *(float4*)&qs[row8][seg * 8 + 4] =
                make_float4(bf2f(qp[4]), bf2f(qp[5]), bf2f(qp[6]), bf2f(qp[7]));
        }
        __syncthreads();
#pragma unroll
        for (int i = 0; i < 8; i++) {
            const float4* q4 = (const float4*)&qs[i][h * 32];
            float s = 0.f;
#pragma unroll
            for (int e4 = 0; e4 < 8; e4++) {
                float4 qv = q4[e4];
                s = fmaf(at[e4 * 4 + 0], qv.x, s);
                s = fmaf(at[e4 * 4 + 1], qv.y, s);
                s = fmaf(at[e4 * 4 + 2], qv.z, s);
                s = fmaf(at[e4 * 4 + 3], qv.w, s);
            }
            int n = nbase + t0 + i;
            out[((size_t)b * NTOK + n) * CDIM + tid] = __float2bfloat16(s);
        }
    }
}

extern "C" void kernel_launch(void* const* d_in, const int* in_sizes, int n_in,
                              void* d_out, int out_size, void* d_ws, size_t ws_size,
                              hipStream_t stream) {
    const float* x      = (const float*)d_in[0];
    const float* cpe1_w = (const float*)d_in[1];
    const float* cpe1_b = (const float*)d_in[2];
    const float* n1g    = (const float*)d_in[3];
    const float* n1b    = (const float*)d_in[4];
    const float* qkv_w  = (const float*)d_in[5];
    const float* proj_w = (const float*)d_in[6];
    const float* proj_b = (const float*)d_in[7];
    const float* cpe2_w = (const float*)d_in[8];
    const float* cpe2_b = (const float*)d_in[9];
    const float* n2g    = (const float*)d_in[10];
    const float* n2b    = (const float*)d_in[11];
    const float* fc1_w  = (const float*)d_in[12];
    const float* fc1_b  = (const float*)d_in[13];
    const float* fc2_w  = (const float*)d_in[14];
    const float* fc2_b  = (const float*)d_in[15];

    const size_t A = (size_t)BN * CDIM;        // 9,633,792
    const size_t HA = A / 2;

    // bf16 weights contiguous at front of ws
    bf16* wqkv  = (bf16*)d_ws;                 // 442368
    bf16* wproj = wqkv + 442368;               // 147456
    bf16* wfc1  = wproj + 147456;              // 589824
    bf16* wfc2  = wfc1 + 589824;               // 589824
    float* base = (float*)d_ws + 884736;

    float* xt        = base;                   // [0, A)        residual stream
    bf16*  curb      = (bf16*)(base + A);      // [A, 1.5A)     LN1 out (bf16)
    bf16*  ylnb      = (bf16*)(base + A);      // phase-2 reuse LN2 out (bf16)
    bf16*  qkvb      = (bf16*)(base + A + HA); // [1.5A, 3A)    qkv (bf16, 3A elems)
    float* x3        = base + A + HA;          // phase-2 reuse [1.5A, 2.5A)
    bf16*  h1        = (bf16*)(base + A + HA + A); // [2.5A, 4.5A) fc1 out (bf16)
    float* attnm     = base + 3 * A;           // [3A, +393216)
    bf16*  attn_outb = (bf16*)(base + 3 * A + 393216);
    float* cpe2_wt   = base + (A * 9) / 2;     // [4.5A, +3456) transposed taps

    const int GEMM_GRID3  = 8 * PERXCD * 3;    // 600
    const int GEMM_GRID9  = 8 * PERXCD * 9;    // 1800
    const int GEMM_GRID12 = 8 * PERXCD * 12;   // 2400

    // 0. weight conversion fp32 -> bf16 + cpe2 tap transpose (one launch)
    prep_k<<<6926, 256, 0, stream>>>(qkv_w, proj_w, fc1_w, fc2_w, wqkv,
                                     cpe2_w, cpe2_wt);

    // 1. fused cpe1 + residual + transpose: x (B,C,N) -> xt (B,N,C)
    cpe1_tr_fused<<<dim3(CDIM / 32, 25, BBATCH), dim3(32, 8), 0, stream>>>(
        x, cpe1_w, cpe1_b, xt);
    // 2. LN1 -> bf16 (float4, 32 lanes/token)
    ln1_k<<<BN / 8, 256, 0, stream>>>(xt, n1g, n1b, curb);
    // 3. qkv GEMM (bf16 MFMA, out bf16)
    gemm_mfma<0, false, bf16, false, 384><<<GEMM_GRID9, 256, 0, stream>>>(
        (const short*)curb, (const short*)wqkv, nullptr, nullptr, qkvb, 1152, 9);
    // 4. channel attention matrices + softmax
    attn_k<<<BBATCH * NHEADS, 256, 0, stream>>>(qkvb, attnm);
    // 5. apply attention to q (out bf16)
    apply_attn_k<<<dim3(BBATCH, 14), 384, 0, stream>>>(qkvb, attnm, attn_outb);
    // 6. proj GEMM + bias + residual (in-place into xt)
    gemm_mfma<0, true, float, false, 384><<<GEMM_GRID3, 256, 0, stream>>>(
        (const short*)attn_outb, (const short*)wproj, proj_b, xt, xt, 384, 3);
    // 7+8. fused cpe2 + residual + LN2 (float4; writes x3 fp32 and ylnb bf16)
    cpe2_ln_fused<<<BN / 8, 256, 0, stream>>>(xt, cpe2_wt, cpe2_b, n2g, n2b,
                                              x3, ylnb);
    // 9. fc1 + bias + GELU (out bf16)
    gemm_mfma<1, false, bf16, false, 384><<<GEMM_GRID12, 256, 0, stream>>>(
        (const short*)ylnb, (const short*)wfc1, fc1_b, nullptr, h1, 1536, 12);
    // 10. fc2 + bias + residual(x3), output directly transposed to (B,C,H,W)
    gemm_mfma<0, true, float, true, 1536><<<GEMM_GRID3, 256, 0, stream>>>(
        (const short*)h1, (const short*)wfc2, fc2_b, x3, (float*)d_out, 384, 3);
}